// Round 3
// baseline (4730.451 us; speedup 1.0000x reference)
//
#include <hip/hip_runtime.h>
#include <math.h>

#define NU 50000
#define NI 50000
#define NT 100000
#define DD 64
#define NBATCH 4096
#define INV_TEMP 5.0f
#define EPS_ 0.2f

#define BROWS 64
#define NBUK ((NT + BROWS - 1) / BROWS)   // 1563
#define ND ((long long)NT * DD)           // 6,400,000 floats

// ---------------- bucket histogram (LDS-aggregated) ----------------
__global__ void bucket_hist_kernel(const int* __restrict__ rows, int E, int* __restrict__ bcnt) {
    __shared__ int h[NBUK];
    int t = threadIdx.x;
    for (int k = t; k < NBUK; k += 256) h[k] = 0;
    __syncthreads();
    for (int e = blockIdx.x * blockDim.x + t; e < E; e += gridDim.x * blockDim.x)
        atomicAdd(&h[rows[e] >> 6], 1);
    __syncthreads();
    for (int k = t; k < NBUK; k += 256) {
        int v = h[k];
        if (v) atomicAdd(&bcnt[k], v);
    }
}

// ---------------- exclusive scan over bucket counts (single block) ----------------
__global__ void bucket_scan_kernel(const int* __restrict__ cnt, int* __restrict__ starts,
                                   int* __restrict__ cur) {
    __shared__ int sd[1024];
    __shared__ int carry;
    int t = threadIdx.x;
    if (t == 0) carry = 0;
    __syncthreads();
    for (int base = 0; base < NBUK; base += 1024) {
        int i = base + t;
        int v = (i < NBUK) ? cnt[i] : 0;
        sd[t] = v;
        __syncthreads();
        #pragma unroll
        for (int o = 1; o < 1024; o <<= 1) {
            int add = (t >= o) ? sd[t - o] : 0;
            __syncthreads();
            sd[t] += add;
            __syncthreads();
        }
        int ex = sd[t] - v + carry;
        if (i < NBUK) { starts[i] = ex; cur[i] = ex; }
        __syncthreads();
        if (t == 1023) carry += sd[1023];
        __syncthreads();
    }
    if (t == 0) starts[NBUK] = carry;   // == E
}

// ---------------- partition: edges -> bucket regions, packed {rl<<17|col, val} ----------------
__global__ void partition_kernel(const int* __restrict__ rows, const int* __restrict__ cols,
                                 const float* __restrict__ vals, int E,
                                 int* __restrict__ cur, int2* __restrict__ edges) {
    int e = blockIdx.x * blockDim.x + threadIdx.x;
    if (e >= E) return;
    int r = rows[e];
    int b = r >> 6;
    int p = atomicAdd(&cur[b], 1);
    edges[p] = make_int2(((r & 63) << 17) | cols[e], __float_as_int(vals[e]));
}

// ---------------- SpMM: block per bucket, LDS accumulator, fused perturb ----------------
// y[row] = sum_e v*x[col] over edges of row, then += sign * l2norm(noise_row) * EPS.
// Input is "virtual concat": col < NU reads xu, else xi (identical when xu,xi point into one buffer).
__global__ void spmm_lds_kernel(const int* __restrict__ bstarts, const int2* __restrict__ edges,
                                const float* __restrict__ xu, const float* __restrict__ xi,
                                const float* __restrict__ noise, float* __restrict__ y) {
    __shared__ float acc[BROWS * DD];   // 16 KB
    int t = threadIdx.x;
    for (int k = t; k < BROWS * DD; k += 256) acc[k] = 0.f;
    __syncthreads();
    int b0 = bstarts[blockIdx.x];
    int bcnt = bstarts[blockIdx.x + 1] - b0;
    int lane = t & 63;
    int w = t >> 6;
    for (int base = w * 64; base < bcnt; base += 256) {
        int k = base + lane;
        int2 ed = (k < bcnt) ? edges[b0 + k] : make_int2(0, 0);
        int lim = min(64, bcnt - base);
        if (lim == 64) {
            #pragma unroll 8
            for (int j = 0; j < 64; ++j) {
                int pk = __shfl(ed.x, j);
                float v = __int_as_float(__shfl(ed.y, j));
                int c = pk & 0x1FFFF;
                int rl = pk >> 17;
                const float* src = (c < NU) ? (xu + (size_t)c * DD) : (xi + (size_t)(c - NU) * DD);
                atomicAdd(&acc[rl * DD + lane], v * src[lane]);
            }
        } else {
            for (int j = 0; j < lim; ++j) {
                int pk = __shfl(ed.x, j);
                float v = __int_as_float(__shfl(ed.y, j));
                int c = pk & 0x1FFFF;
                int rl = pk >> 17;
                const float* src = (c < NU) ? (xu + (size_t)c * DD) : (xi + (size_t)(c - NU) * DD);
                atomicAdd(&acc[rl * DD + lane], v * src[lane]);
            }
        }
    }
    __syncthreads();
    // writeout + fused perturb: each wave handles rows w, w+4, ...
    for (int rl = w; rl < BROWS; rl += 4) {
        int row = blockIdx.x * BROWS + rl;
        if (row >= NT) break;
        float a = acc[rl * DD + lane];
        float nz = noise[(size_t)row * DD + lane];
        float s = nz * nz;
        #pragma unroll
        for (int o = 32; o > 0; o >>= 1) s += __shfl_xor(s, o);
        float norm = fmaxf(sqrtf(s), 1e-12f);
        float sg = (a > 0.f) ? 1.f : ((a < 0.f) ? -1.f : 0.f);
        y[(size_t)row * DD + lane] = a + sg * (nz / norm) * EPS_;
    }
}

// ---------------- unique via flags ----------------
__global__ void unique_kernel(const int* __restrict__ in, int n, int* __restrict__ flags,
                              int* __restrict__ list, int* __restrict__ count) {
    int t = blockIdx.x * blockDim.x + threadIdx.x;
    if (t >= n) return;
    int u = in[t];
    if (atomicExch(&flags[u], 1) == 0) {
        int p = atomicAdd(count, 1);
        list[p] = u;
    }
}

// ---------------- gather + normalize v1 (light_out) & v2 (emb_cl), pos score ----------------
__global__ void gather_cl_kernel(const int* __restrict__ list, const int* __restrict__ count,
                                 int baseRow,
                                 const float* __restrict__ A, const float* __restrict__ B,
                                 const float* __restrict__ C,
                                 float* __restrict__ V1, float* __restrict__ V2,
                                 float* __restrict__ posv) {
    int gid = blockIdx.x * blockDim.x + threadIdx.x;
    int s = gid >> 6;
    int lane = gid & 63;
    if (s >= NBATCH) return;
    int cnt = *count;
    float v1 = 0.f, v2 = 0.f;
    if (s < cnt) {
        int r = (baseRow + list[s]) * DD + lane;
        v1 = (A[r] + B[r] + C[r]) * (1.f / 3.f);
        v2 = B[r];    // emb_cl = layer-1 perturbed output
    }
    float s1 = v1 * v1, s2 = v2 * v2;
    #pragma unroll
    for (int o = 32; o > 0; o >>= 1) { s1 += __shfl_xor(s1, o); s2 += __shfl_xor(s2, o); }
    v1 = v1 / fmaxf(sqrtf(s1), 1e-12f);
    v2 = v2 / fmaxf(sqrtf(s2), 1e-12f);
    V1[s * DD + lane] = v1;
    V2[s * DD + lane] = v2;
    float d = v1 * v2;
    #pragma unroll
    for (int o = 32; o > 0; o >>= 1) d += __shfl_xor(d, o);
    if (lane == 0) posv[s] = __expf(d * INV_TEMP);
}

// ---------------- ttl: 64x64 output tile per block, 4x4 register tiling ----------------
__global__ void ttl_kernel(const float* __restrict__ V1, const float* __restrict__ V2,
                           const int* __restrict__ count, float* __restrict__ ttl) {
    __shared__ float sA[64 * 68];   // transposed: [d][i]
    __shared__ float sB[64 * 68];   // transposed: [d][j]
    __shared__ float red[64];
    int cnt = *count;
    int i0 = blockIdx.x * 64;
    int j0 = blockIdx.y * 64;
    if (j0 >= cnt) return;
    int t = threadIdx.x;   // 256
    for (int k = t; k < 64 * 64; k += 256) {
        int r = k >> 6, d = k & 63;
        sA[d * 68 + r] = V1[(i0 + r) * DD + d];
        sB[d * 68 + r] = V2[(j0 + r) * DD + d];
    }
    if (t < 64) red[t] = 0.f;
    __syncthreads();
    int tx = t & 15;
    int ty = t >> 4;
    float acc[4][4] = {{0.f}};
    for (int d = 0; d < 64; ++d) {
        float4 a = *(const float4*)&sA[d * 68 + ty * 4];
        float4 b = *(const float4*)&sB[d * 68 + tx * 4];
        acc[0][0] += a.x * b.x; acc[0][1] += a.x * b.y; acc[0][2] += a.x * b.z; acc[0][3] += a.x * b.w;
        acc[1][0] += a.y * b.x; acc[1][1] += a.y * b.y; acc[1][2] += a.y * b.z; acc[1][3] += a.y * b.w;
        acc[2][0] += a.z * b.x; acc[2][1] += a.z * b.y; acc[2][2] += a.z * b.z; acc[2][3] += a.z * b.w;
        acc[3][0] += a.w * b.x; acc[3][1] += a.w * b.y; acc[3][2] += a.w * b.z; acc[3][3] += a.w * b.w;
    }
    #pragma unroll
    for (int ii = 0; ii < 4; ++ii) {
        float rs = 0.f;
        #pragma unroll
        for (int jj = 0; jj < 4; ++jj) {
            int j = j0 + tx * 4 + jj;
            if (j < cnt) rs += __expf(acc[ii][jj] * INV_TEMP);
        }
        atomicAdd(&red[ty * 4 + ii], rs);
    }
    __syncthreads();
    if (t < 64) atomicAdd(&ttl[i0 + t], red[t]);
}

// ---------------- cl partial ----------------
__global__ void cl_reduce_kernel(const float* __restrict__ posv, const float* __restrict__ ttl,
                                 const int* __restrict__ count, float* __restrict__ acc) {
    int t = blockIdx.x * blockDim.x + threadIdx.x;
    if (t >= NBATCH) return;
    int cnt = *count;
    float term = 0.f;
    if (t < cnt) term = -logf(posv[t] / ttl[t] + 1e-5f);
    #pragma unroll
    for (int o = 32; o > 0; o >>= 1) term += __shfl_xor(term, o);
    if ((t & 63) == 0) atomicAdd(acc, term);
}

// ---------------- BPR + reg ----------------
__global__ void bpr_kernel(const int* __restrict__ users, const int* __restrict__ pos,
                           const int* __restrict__ neg,
                           const float* __restrict__ A, const float* __restrict__ B,
                           const float* __restrict__ C,
                           const float* __restrict__ user_emb, const float* __restrict__ item_emb,
                           float* __restrict__ mf_acc, float* __restrict__ reg_acc) {
    int gid = blockIdx.x * blockDim.x + threadIdx.x;
    int b = gid >> 6;
    int lane = gid & 63;
    if (b >= NBATCH) return;
    int u = users[b], p = pos[b], n = neg[b];
    int ru = u * DD + lane;
    int rp = (NU + p) * DD + lane;
    int rn = (NU + n) * DD + lane;
    float ue = (A[ru] + B[ru] + C[ru]) * (1.f / 3.f);
    float pe = (A[rp] + B[rp] + C[rp]) * (1.f / 3.f);
    float ne = (A[rn] + B[rn] + C[rn]) * (1.f / 3.f);
    float su = ue * ue, sp = pe * pe, sn = ne * ne, dp = ue * pe, dn = ue * ne;
    float u0 = user_emb[u * DD + lane];
    float p0 = item_emb[p * DD + lane];
    float n0 = item_emb[n * DD + lane];
    float rg = u0 * u0 + p0 * p0 + n0 * n0;
    #pragma unroll
    for (int o = 32; o > 0; o >>= 1) {
        su += __shfl_xor(su, o); sp += __shfl_xor(sp, o); sn += __shfl_xor(sn, o);
        dp += __shfl_xor(dp, o); dn += __shfl_xor(dn, o); rg += __shfl_xor(rg, o);
    }
    if (lane == 0) {
        float nu = fmaxf(sqrtf(su), 1e-12f);
        float np_ = fmaxf(sqrtf(sp), 1e-12f);
        float nn_ = fmaxf(sqrtf(sn), 1e-12f);
        float ps = dp / (nu * np_);
        float ns = dn / (nu * nn_);
        float x = ps - ns;
        float sig = 1.f / (1.f + __expf(-x));
        atomicAdd(mf_acc, logf(sig + 1e-6f));
        atomicAdd(reg_acc, rg);
    }
}

// ---------------- finalize ----------------
__global__ void finalize_kernel(const float* __restrict__ mf_acc, const float* __restrict__ reg_acc,
                                const float* __restrict__ clu, const float* __restrict__ cli,
                                const int* __restrict__ cntu, const int* __restrict__ cnti,
                                float* __restrict__ out) {
    if (threadIdx.x == 0 && blockIdx.x == 0) {
        out[0] = -(*mf_acc) / (float)NBATCH;
        out[1] = 0.2f * ((*clu) / (float)(*cntu) + (*cli) / (float)(*cnti));
        out[2] = 1e-4f * 0.5f * (*reg_acc) / (float)NBATCH;
    }
}

extern "C" void kernel_launch(void* const* d_in, const int* in_sizes, int n_in,
                              void* d_out, int out_size, void* d_ws, size_t ws_size,
                              hipStream_t stream) {
    const int*   users     = (const int*)d_in[0];
    const int*   pos_items = (const int*)d_in[1];
    const int*   neg_items = (const int*)d_in[2];
    const float* user_emb  = (const float*)d_in[3];
    const float* item_emb  = (const float*)d_in[4];
    const int*   rows      = (const int*)d_in[5];
    const int*   cols      = (const int*)d_in[6];
    const float* vals      = (const float*)d_in[7];
    const float* noise     = (const float*)d_in[8];
    float* out = (float*)d_out;
    const int E = in_sizes[5];

    // ---- workspace carve (256B aligned) ----
    char* w = (char*)d_ws;
    size_t off = 0;
    auto carve = [&](size_t bytes) { char* p = w + off; off = (off + bytes + 255) & ~(size_t)255; return p; };
    float* bufA = (float*)carve(ND * 4);
    float* bufB = (float*)carve(ND * 4);
    float* bufC = (float*)carve(ND * 4);
    int2*  edges   = (int2*)carve((size_t)E * 8);
    int*   bcnt    = (int*)carve(NBUK * 4);
    int*   bstarts = (int*)carve((NBUK + 1) * 4);
    int*   bcur    = (int*)carve(NBUK * 4);
    int* flags_u = (int*)carve(NU * 4);
    int* flags_i = (int*)carve(NI * 4);
    int* ulist   = (int*)carve(NBATCH * 4);
    int* ilist   = (int*)carve(NBATCH * 4);
    int* cnts    = (int*)carve(2 * 4);            // [0]=u, [1]=i
    float* V1u = (float*)carve((size_t)NBATCH * DD * 4);
    float* V2u = (float*)carve((size_t)NBATCH * DD * 4);
    float* V1i = (float*)carve((size_t)NBATCH * DD * 4);
    float* V2i = (float*)carve((size_t)NBATCH * DD * 4);
    float* pos_u = (float*)carve(NBATCH * 4);
    float* pos_i = (float*)carve(NBATCH * 4);
    float* ttl_u = (float*)carve(NBATCH * 4);
    float* ttl_i = (float*)carve(NBATCH * 4);
    float* accum = (float*)carve(4 * 4);          // [0]=mf, [1]=reg, [2]=clu, [3]=cli

    // ---- zero small scratch ----
    hipMemsetAsync(bcnt, 0, NBUK * 4, stream);
    hipMemsetAsync(flags_u, 0, NU * 4, stream);
    hipMemsetAsync(flags_i, 0, NI * 4, stream);
    hipMemsetAsync(cnts, 0, 2 * 4, stream);
    hipMemsetAsync(accum, 0, 4 * 4, stream);
    hipMemsetAsync(ttl_u, 0, NBATCH * 4, stream);
    hipMemsetAsync(ttl_i, 0, NBATCH * 4, stream);

    const int edgeBlocks = (E + 255) / 256;
    const int slotBlocks = (NBATCH * DD + 255) / 256;

    // ---- bucketed edge build ----
    bucket_hist_kernel<<<312, 256, 0, stream>>>(rows, E, bcnt);
    bucket_scan_kernel<<<1, 1024, 0, stream>>>(bcnt, bstarts, bcur);
    partition_kernel<<<edgeBlocks, 256, 0, stream>>>(rows, cols, vals, E, bcur, edges);

    // ---- 3 propagation layers (perturb fused), virtual concat on layer 1 ----
    spmm_lds_kernel<<<NBUK, 256, 0, stream>>>(bstarts, edges, user_emb, item_emb,
                                              noise + 0 * ND, bufB);
    spmm_lds_kernel<<<NBUK, 256, 0, stream>>>(bstarts, edges, bufB, bufB + (size_t)NU * DD,
                                              noise + 1 * ND, bufC);
    spmm_lds_kernel<<<NBUK, 256, 0, stream>>>(bstarts, edges, bufC, bufC + (size_t)NU * DD,
                                              noise + 2 * ND, bufA);

    // ---- unique ----
    unique_kernel<<<(NBATCH + 255) / 256, 256, 0, stream>>>(users, NBATCH, flags_u, ulist, &cnts[0]);
    unique_kernel<<<(NBATCH + 255) / 256, 256, 0, stream>>>(pos_items, NBATCH, flags_i, ilist, &cnts[1]);

    // ---- gather + normalize + pos scores ----
    gather_cl_kernel<<<slotBlocks, 256, 0, stream>>>(ulist, &cnts[0], 0,  bufA, bufB, bufC, V1u, V2u, pos_u);
    gather_cl_kernel<<<slotBlocks, 256, 0, stream>>>(ilist, &cnts[1], NU, bufA, bufB, bufC, V1i, V2i, pos_i);

    // ---- ttl sums ----
    dim3 tgrid(NBATCH / 64, NBATCH / 64);
    ttl_kernel<<<tgrid, 256, 0, stream>>>(V1u, V2u, &cnts[0], ttl_u);
    ttl_kernel<<<tgrid, 256, 0, stream>>>(V1i, V2i, &cnts[1], ttl_i);

    // ---- cl partial sums ----
    cl_reduce_kernel<<<(NBATCH + 255) / 256, 256, 0, stream>>>(pos_u, ttl_u, &cnts[0], &accum[2]);
    cl_reduce_kernel<<<(NBATCH + 255) / 256, 256, 0, stream>>>(pos_i, ttl_i, &cnts[1], &accum[3]);

    // ---- BPR + reg ----
    bpr_kernel<<<slotBlocks, 256, 0, stream>>>(users, pos_items, neg_items, bufA, bufB, bufC,
                                               user_emb, item_emb, &accum[0], &accum[1]);

    // ---- finalize ----
    finalize_kernel<<<1, 64, 0, stream>>>(&accum[0], &accum[1], &accum[2], &accum[3],
                                          &cnts[0], &cnts[1], out);
}

// Round 4
// 1311.887 us; speedup vs baseline: 3.6058x; 3.6058x over previous
//
#include <hip/hip_runtime.h>
#include <hip/hip_fp16.h>
#include <math.h>

#define NU 50000
#define NI 50000
#define NT 100000
#define DD 64
#define NBATCH 4096
#define INV_TEMP 5.0f
#define EPS_ 0.2f

#define BROWS 64
#define NBUK ((NT + BROWS - 1) / BROWS)   // 1563
#define ND ((long long)NT * DD)           // 6,400,000
#define SCAN_BLOCKS ((NT + 255) / 256)    // 391

// ---------------- per-row degree histogram ----------------
__global__ void hist_kernel(const int* __restrict__ rows, int E, int* __restrict__ deg) {
    int e = blockIdx.x * blockDim.x + threadIdx.x;
    if (e < E) atomicAdd(&deg[rows[e]], 1);
}

// ---------------- scan phase 1: per-256-block exclusive partials ----------------
__global__ void scan1_kernel(const int* __restrict__ deg, int* __restrict__ rstart,
                             int* __restrict__ bt) {
    __shared__ int wsum[4];
    int t = threadIdx.x;
    int i = blockIdx.x * 256 + t;
    int v = (i < NT) ? deg[i] : 0;
    int lane = t & 63, wid = t >> 6;
    int x = v;
    #pragma unroll
    for (int o = 1; o < 64; o <<= 1) { int y = __shfl_up(x, o); if (lane >= o) x += y; }
    if (lane == 63) wsum[wid] = x;
    __syncthreads();
    if (t == 0) {
        int s = 0;
        #pragma unroll
        for (int k = 0; k < 4; ++k) { int tmp = wsum[k]; wsum[k] = s; s += tmp; }
        bt[blockIdx.x] = s;
    }
    __syncthreads();
    if (i < NT) rstart[i] = x - v + wsum[wid];
}

// ---------------- scan phase 2: scan the 391 block totals ----------------
__global__ void scan2_kernel(int* __restrict__ bt, int* __restrict__ bt2,
                             int* __restrict__ rstart) {
    __shared__ int wsum[8];
    int t = threadIdx.x;   // 512
    int v = (t < SCAN_BLOCKS) ? bt[t] : 0;
    int lane = t & 63, wid = t >> 6;
    int x = v;
    #pragma unroll
    for (int o = 1; o < 64; o <<= 1) { int y = __shfl_up(x, o); if (lane >= o) x += y; }
    if (lane == 63) wsum[wid] = x;
    __syncthreads();
    if (t == 0) {
        int s = 0;
        #pragma unroll
        for (int k = 0; k < 8; ++k) { int tmp = wsum[k]; wsum[k] = s; s += tmp; }
        rstart[NT] = s;   // grand total == E
    }
    __syncthreads();
    if (t < SCAN_BLOCKS) bt2[t] = x - v + wsum[wid];
}

// ---------------- scan phase 3: add block offsets; init bucket cursors ----------------
__global__ void scan3_kernel(int* __restrict__ rstart, const int* __restrict__ bt2,
                             int* __restrict__ bcur) {
    int i = blockIdx.x * 256 + threadIdx.x;
    if (i >= NT) return;
    int v = rstart[i] + bt2[blockIdx.x];
    rstart[i] = v;
    if ((i & 63) == 0) bcur[i >> 6] = v;
}

// ---------------- partition: edges -> bucket regions, packed {rl<<17|col, val} ----------------
__global__ void partition_kernel(const int* __restrict__ rows, const int* __restrict__ cols,
                                 const float* __restrict__ vals, int E,
                                 int* __restrict__ bcur, int2* __restrict__ bedges) {
    int e = blockIdx.x * blockDim.x + threadIdx.x;
    if (e >= E) return;
    int r = rows[e];
    int p = atomicAdd(&bcur[r >> 6], 1);
    bedges[p] = make_int2(((r & 63) << 17) | cols[e], __float_as_int(vals[e]));
}

// ---------------- in-bucket counting sort into exact CSR slots ----------------
__global__ void bucket_sort_kernel(const int* __restrict__ rstart,
                                   const int2* __restrict__ bedges,
                                   int2* __restrict__ edges) {
    __shared__ int lcur[BROWS];
    int b = blockIdx.x;
    int r0 = b * BROWS;
    int nrows = min(BROWS, NT - r0);
    int t = threadIdx.x;
    if (t < nrows) lcur[t] = rstart[r0 + t];
    __syncthreads();
    int e0 = rstart[r0];
    int e1 = rstart[min(r0 + BROWS, NT)];
    for (int k = e0 + t; k < e1; k += 256) {
        int2 ed = bedges[k];
        int rl = ed.x >> 17;
        int col = ed.x & 0x1FFFF;
        int p = atomicAdd(&lcur[rl], 1);
        edges[p] = make_int2(col, ed.y);
    }
}

// ---------------- fp32 concat -> fp16 ----------------
__global__ void concat_half_kernel(const float* __restrict__ u, const float* __restrict__ it,
                                   __half* __restrict__ x0) {
    long long i = (long long)blockIdx.x * 256 + threadIdx.x;
    if (i >= ND) return;
    long long half1 = (long long)NU * DD;
    float v = (i < half1) ? u[i] : it[i - half1];
    x0[i] = (__half)v;
}

// ---------------- SpMM (CSR, wave per row, fp16 gather) + fused perturb ----------------
__global__ void spmm_csr_kernel(const int* __restrict__ rstart, const int2* __restrict__ edges,
                                const __half* __restrict__ x, const float* __restrict__ noise,
                                __half* __restrict__ y) {
    int gid = blockIdx.x * blockDim.x + threadIdx.x;
    int row = gid >> 6;
    int lane = gid & 63;
    if (row >= NT) return;
    int s0 = rstart[row];
    int s1 = rstart[row + 1];
    float acc = 0.f;
    for (int base = s0; base < s1; base += 64) {
        int k = base + lane;
        int2 ed = (k < s1) ? edges[k] : make_int2(0, 0);
        int lim = min(64, s1 - base);
        int j = 0;
        for (; j + 8 <= lim; j += 8) {
            #pragma unroll
            for (int u = 0; u < 8; ++u) {
                int c = __shfl(ed.x, j + u);
                float v = __int_as_float(__shfl(ed.y, j + u));
                acc += v * (float)x[c * DD + lane];
            }
        }
        for (; j < lim; ++j) {
            int c = __shfl(ed.x, j);
            float v = __int_as_float(__shfl(ed.y, j));
            acc += v * (float)x[c * DD + lane];
        }
    }
    // perturb: acc + sign(acc) * (noise_row / ||noise_row||) * EPS
    float nz = noise[(size_t)row * DD + lane];
    float s = nz * nz;
    #pragma unroll
    for (int o = 32; o > 0; o >>= 1) s += __shfl_xor(s, o);
    float norm = fmaxf(sqrtf(s), 1e-12f);
    float sg = (acc > 0.f) ? 1.f : ((acc < 0.f) ? -1.f : 0.f);
    y[(size_t)row * DD + lane] = (__half)(acc + sg * (nz / norm) * EPS_);
}

// ---------------- unique via flags ----------------
__global__ void unique_kernel(const int* __restrict__ in, int n, int* __restrict__ flags,
                              int* __restrict__ list, int* __restrict__ count) {
    int t = blockIdx.x * blockDim.x + threadIdx.x;
    if (t >= n) return;
    int u = in[t];
    if (atomicExch(&flags[u], 1) == 0) {
        int p = atomicAdd(count, 1);
        list[p] = u;
    }
}

// ---------------- gather + normalize v1 (light_out) & v2 (emb_cl), pos score ----------------
__global__ void gather_cl_kernel(const int* __restrict__ list, const int* __restrict__ count,
                                 int baseRow,
                                 const __half* __restrict__ A, const __half* __restrict__ B,
                                 const __half* __restrict__ C,
                                 float* __restrict__ V1, float* __restrict__ V2,
                                 float* __restrict__ posv) {
    int gid = blockIdx.x * blockDim.x + threadIdx.x;
    int s = gid >> 6;
    int lane = gid & 63;
    if (s >= NBATCH) return;
    int cnt = *count;
    float v1 = 0.f, v2 = 0.f;
    if (s < cnt) {
        size_t r = (size_t)(baseRow + list[s]) * DD + lane;
        v1 = ((float)A[r] + (float)B[r] + (float)C[r]) * (1.f / 3.f);
        v2 = (float)B[r];    // emb_cl = layer-1 perturbed output
    }
    float s1 = v1 * v1, s2 = v2 * v2;
    #pragma unroll
    for (int o = 32; o > 0; o >>= 1) { s1 += __shfl_xor(s1, o); s2 += __shfl_xor(s2, o); }
    v1 = v1 / fmaxf(sqrtf(s1), 1e-12f);
    v2 = v2 / fmaxf(sqrtf(s2), 1e-12f);
    V1[s * DD + lane] = v1;
    V2[s * DD + lane] = v2;
    float d = v1 * v2;
    #pragma unroll
    for (int o = 32; o > 0; o >>= 1) d += __shfl_xor(d, o);
    if (lane == 0) posv[s] = __expf(d * INV_TEMP);
}

// ---------------- ttl: 64x64 output tile per block, 4x4 register tiling ----------------
__global__ void ttl_kernel(const float* __restrict__ V1, const float* __restrict__ V2,
                           const int* __restrict__ count, float* __restrict__ ttl) {
    __shared__ float sA[64 * 68];   // transposed: [d][i]
    __shared__ float sB[64 * 68];   // transposed: [d][j]
    __shared__ float red[64];
    int cnt = *count;
    int i0 = blockIdx.x * 64;
    int j0 = blockIdx.y * 64;
    if (j0 >= cnt) return;
    int t = threadIdx.x;   // 256
    for (int k = t; k < 64 * 64; k += 256) {
        int r = k >> 6, d = k & 63;
        sA[d * 68 + r] = V1[(i0 + r) * DD + d];
        sB[d * 68 + r] = V2[(j0 + r) * DD + d];
    }
    if (t < 64) red[t] = 0.f;
    __syncthreads();
    int tx = t & 15;
    int ty = t >> 4;
    float acc[4][4] = {{0.f}};
    for (int d = 0; d < 64; ++d) {
        float4 a = *(const float4*)&sA[d * 68 + ty * 4];
        float4 b = *(const float4*)&sB[d * 68 + tx * 4];
        acc[0][0] += a.x * b.x; acc[0][1] += a.x * b.y; acc[0][2] += a.x * b.z; acc[0][3] += a.x * b.w;
        acc[1][0] += a.y * b.x; acc[1][1] += a.y * b.y; acc[1][2] += a.y * b.z; acc[1][3] += a.y * b.w;
        acc[2][0] += a.z * b.x; acc[2][1] += a.z * b.y; acc[2][2] += a.z * b.z; acc[2][3] += a.z * b.w;
        acc[3][0] += a.w * b.x; acc[3][1] += a.w * b.y; acc[3][2] += a.w * b.z; acc[3][3] += a.w * b.w;
    }
    #pragma unroll
    for (int ii = 0; ii < 4; ++ii) {
        float rs = 0.f;
        #pragma unroll
        for (int jj = 0; jj < 4; ++jj) {
            int j = j0 + tx * 4 + jj;
            if (j < cnt) rs += __expf(acc[ii][jj] * INV_TEMP);
        }
        atomicAdd(&red[ty * 4 + ii], rs);
    }
    __syncthreads();
    if (t < 64) atomicAdd(&ttl[i0 + t], red[t]);
}

// ---------------- cl partial ----------------
__global__ void cl_reduce_kernel(const float* __restrict__ posv, const float* __restrict__ ttl,
                                 const int* __restrict__ count, float* __restrict__ acc) {
    int t = blockIdx.x * blockDim.x + threadIdx.x;
    if (t >= NBATCH) return;
    int cnt = *count;
    float term = 0.f;
    if (t < cnt) term = -logf(posv[t] / ttl[t] + 1e-5f);
    #pragma unroll
    for (int o = 32; o > 0; o >>= 1) term += __shfl_xor(term, o);
    if ((t & 63) == 0) atomicAdd(acc, term);
}

// ---------------- BPR + reg ----------------
__global__ void bpr_kernel(const int* __restrict__ users, const int* __restrict__ pos,
                           const int* __restrict__ neg,
                           const __half* __restrict__ A, const __half* __restrict__ B,
                           const __half* __restrict__ C,
                           const float* __restrict__ user_emb, const float* __restrict__ item_emb,
                           float* __restrict__ mf_acc, float* __restrict__ reg_acc) {
    int gid = blockIdx.x * blockDim.x + threadIdx.x;
    int b = gid >> 6;
    int lane = gid & 63;
    if (b >= NBATCH) return;
    int u = users[b], p = pos[b], n = neg[b];
    size_t ru = (size_t)u * DD + lane;
    size_t rp = (size_t)(NU + p) * DD + lane;
    size_t rn = (size_t)(NU + n) * DD + lane;
    float ue = ((float)A[ru] + (float)B[ru] + (float)C[ru]) * (1.f / 3.f);
    float pe = ((float)A[rp] + (float)B[rp] + (float)C[rp]) * (1.f / 3.f);
    float ne = ((float)A[rn] + (float)B[rn] + (float)C[rn]) * (1.f / 3.f);
    float su = ue * ue, sp = pe * pe, sn = ne * ne, dp = ue * pe, dn = ue * ne;
    float u0 = user_emb[(size_t)u * DD + lane];
    float p0 = item_emb[(size_t)p * DD + lane];
    float n0 = item_emb[(size_t)n * DD + lane];
    float rg = u0 * u0 + p0 * p0 + n0 * n0;
    #pragma unroll
    for (int o = 32; o > 0; o >>= 1) {
        su += __shfl_xor(su, o); sp += __shfl_xor(sp, o); sn += __shfl_xor(sn, o);
        dp += __shfl_xor(dp, o); dn += __shfl_xor(dn, o); rg += __shfl_xor(rg, o);
    }
    if (lane == 0) {
        float nu = fmaxf(sqrtf(su), 1e-12f);
        float np_ = fmaxf(sqrtf(sp), 1e-12f);
        float nn_ = fmaxf(sqrtf(sn), 1e-12f);
        float ps = dp / (nu * np_);
        float ns = dn / (nu * nn_);
        float x = ps - ns;
        float sig = 1.f / (1.f + __expf(-x));
        atomicAdd(mf_acc, logf(sig + 1e-6f));
        atomicAdd(reg_acc, rg);
    }
}

// ---------------- finalize ----------------
__global__ void finalize_kernel(const float* __restrict__ mf_acc, const float* __restrict__ reg_acc,
                                const float* __restrict__ clu, const float* __restrict__ cli,
                                const int* __restrict__ cntu, const int* __restrict__ cnti,
                                float* __restrict__ out) {
    if (threadIdx.x == 0 && blockIdx.x == 0) {
        out[0] = -(*mf_acc) / (float)NBATCH;
        out[1] = 0.2f * ((*clu) / (float)(*cntu) + (*cli) / (float)(*cnti));
        out[2] = 1e-4f * 0.5f * (*reg_acc) / (float)NBATCH;
    }
}

extern "C" void kernel_launch(void* const* d_in, const int* in_sizes, int n_in,
                              void* d_out, int out_size, void* d_ws, size_t ws_size,
                              hipStream_t stream) {
    const int*   users     = (const int*)d_in[0];
    const int*   pos_items = (const int*)d_in[1];
    const int*   neg_items = (const int*)d_in[2];
    const float* user_emb  = (const float*)d_in[3];
    const float* item_emb  = (const float*)d_in[4];
    const int*   rows      = (const int*)d_in[5];
    const int*   cols      = (const int*)d_in[6];
    const float* vals      = (const float*)d_in[7];
    const float* noise     = (const float*)d_in[8];
    float* out = (float*)d_out;
    const int E = in_sizes[5];

    // ---- workspace carve (256B aligned) ----
    char* w = (char*)d_ws;
    size_t off = 0;
    auto carve = [&](size_t bytes) { char* p = w + off; off = (off + bytes + 255) & ~(size_t)255; return p; };
    __half* bufX = (__half*)carve(ND * 2);     // layer-0 input (fp16)
    __half* bufA = (__half*)carve(ND * 2);     // layer-3 out
    __half* bufB = (__half*)carve(ND * 2);     // layer-1 out (emb_cl)
    __half* bufC = (__half*)carve(ND * 2);     // layer-2 out
    int2*  bedges  = (int2*)carve((size_t)E * 8);
    int2*  edges   = (int2*)carve((size_t)E * 8);
    int*   deg     = (int*)carve(NT * 4);
    int*   rstart  = (int*)carve((NT + 1) * 4);
    int*   bt      = (int*)carve(SCAN_BLOCKS * 4);
    int*   bt2     = (int*)carve(SCAN_BLOCKS * 4);
    int*   bcur    = (int*)carve(NBUK * 4);
    int* flags_u = (int*)carve(NU * 4);
    int* flags_i = (int*)carve(NI * 4);
    int* ulist   = (int*)carve(NBATCH * 4);
    int* ilist   = (int*)carve(NBATCH * 4);
    int* cnts    = (int*)carve(2 * 4);            // [0]=u, [1]=i
    float* V1u = (float*)carve((size_t)NBATCH * DD * 4);
    float* V2u = (float*)carve((size_t)NBATCH * DD * 4);
    float* V1i = (float*)carve((size_t)NBATCH * DD * 4);
    float* V2i = (float*)carve((size_t)NBATCH * DD * 4);
    float* pos_u = (float*)carve(NBATCH * 4);
    float* pos_i = (float*)carve(NBATCH * 4);
    float* ttl_u = (float*)carve(NBATCH * 4);
    float* ttl_i = (float*)carve(NBATCH * 4);
    float* accum = (float*)carve(4 * 4);          // [0]=mf, [1]=reg, [2]=clu, [3]=cli

    // ---- zero small scratch ----
    hipMemsetAsync(deg, 0, NT * 4, stream);
    hipMemsetAsync(flags_u, 0, NU * 4, stream);
    hipMemsetAsync(flags_i, 0, NI * 4, stream);
    hipMemsetAsync(cnts, 0, 2 * 4, stream);
    hipMemsetAsync(accum, 0, 4 * 4, stream);
    hipMemsetAsync(ttl_u, 0, NBATCH * 4, stream);
    hipMemsetAsync(ttl_i, 0, NBATCH * 4, stream);

    const int edgeBlocks = (E + 255) / 256;
    const int rowBlocks  = (NT * DD + 255) / 256;
    const int slotBlocks = (NBATCH * DD + 255) / 256;
    const int ndBlocks   = (int)((ND + 255) / 256);

    // ---- CSR build: hist -> 3-phase scan -> bucket partition -> in-bucket sort ----
    hist_kernel<<<edgeBlocks, 256, 0, stream>>>(rows, E, deg);
    scan1_kernel<<<SCAN_BLOCKS, 256, 0, stream>>>(deg, rstart, bt);
    scan2_kernel<<<1, 512, 0, stream>>>(bt, bt2, rstart);
    scan3_kernel<<<SCAN_BLOCKS, 256, 0, stream>>>(rstart, bt2, bcur);
    partition_kernel<<<edgeBlocks, 256, 0, stream>>>(rows, cols, vals, E, bcur, bedges);
    bucket_sort_kernel<<<NBUK, 256, 0, stream>>>(rstart, bedges, edges);

    // ---- fp16 input concat ----
    concat_half_kernel<<<ndBlocks, 256, 0, stream>>>(user_emb, item_emb, bufX);

    // ---- 3 propagation layers (perturb fused) ----
    spmm_csr_kernel<<<rowBlocks, 256, 0, stream>>>(rstart, edges, bufX, noise + 0 * ND, bufB);
    spmm_csr_kernel<<<rowBlocks, 256, 0, stream>>>(rstart, edges, bufB, noise + 1 * ND, bufC);
    spmm_csr_kernel<<<rowBlocks, 256, 0, stream>>>(rstart, edges, bufC, noise + 2 * ND, bufA);

    // ---- unique ----
    unique_kernel<<<(NBATCH + 255) / 256, 256, 0, stream>>>(users, NBATCH, flags_u, ulist, &cnts[0]);
    unique_kernel<<<(NBATCH + 255) / 256, 256, 0, stream>>>(pos_items, NBATCH, flags_i, ilist, &cnts[1]);

    // ---- gather + normalize + pos scores ----
    gather_cl_kernel<<<slotBlocks, 256, 0, stream>>>(ulist, &cnts[0], 0,  bufA, bufB, bufC, V1u, V2u, pos_u);
    gather_cl_kernel<<<slotBlocks, 256, 0, stream>>>(ilist, &cnts[1], NU, bufA, bufB, bufC, V1i, V2i, pos_i);

    // ---- ttl sums ----
    dim3 tgrid(NBATCH / 64, NBATCH / 64);
    ttl_kernel<<<tgrid, 256, 0, stream>>>(V1u, V2u, &cnts[0], ttl_u);
    ttl_kernel<<<tgrid, 256, 0, stream>>>(V1i, V2i, &cnts[1], ttl_i);

    // ---- cl partial sums ----
    cl_reduce_kernel<<<(NBATCH + 255) / 256, 256, 0, stream>>>(pos_u, ttl_u, &cnts[0], &accum[2]);
    cl_reduce_kernel<<<(NBATCH + 255) / 256, 256, 0, stream>>>(pos_i, ttl_i, &cnts[1], &accum[3]);

    // ---- BPR + reg ----
    bpr_kernel<<<slotBlocks, 256, 0, stream>>>(users, pos_items, neg_items, bufA, bufB, bufC,
                                               user_emb, item_emb, &accum[0], &accum[1]);

    // ---- finalize ----
    finalize_kernel<<<1, 64, 0, stream>>>(&accum[0], &accum[1], &accum[2], &accum[3],
                                          &cnts[0], &cnts[1], out);
}

// Round 5
// 796.939 us; speedup vs baseline: 5.9358x; 1.6462x over previous
//
#include <hip/hip_runtime.h>
#include <hip/hip_fp16.h>
#include <math.h>

#define NU 50000
#define NI 50000
#define NT 100000
#define DD 64
#define NBATCH 4096
#define INV_TEMP 5.0f
#define EPS_ 0.2f

#define CBR 512                            // rows per coarse bucket
#define NCB ((NT + CBR - 1) / CBR)         // 196
#define TILE 8192                          // edges per phase-1 block
#define ND ((long long)NT * DD)            // 6,400,000

// ---------------- coarse histogram: 196 buckets, LDS-aggregated ----------------
__global__ void coarse_hist_kernel(const int* __restrict__ rows, int E, int* __restrict__ ccnt) {
    __shared__ int h[NCB];
    int t = threadIdx.x;
    if (t < NCB) h[t] = 0;
    __syncthreads();
    int base = blockIdx.x * TILE;
    for (int it = 0; it < TILE / 256; ++it) {
        int e = base + it * 256 + t;
        if (e < E) atomicAdd(&h[rows[e] >> 9], 1);
    }
    __syncthreads();
    if (t < NCB && h[t]) atomicAdd(&ccnt[t], h[t]);
}

// ---------------- coarse scan: 196 entries -> cstart[197], ccur; set rstart[NT] ----------------
__global__ void coarse_scan_kernel(const int* __restrict__ ccnt, int* __restrict__ cstart,
                                   int* __restrict__ ccur, int* __restrict__ rstart, int E) {
    __shared__ int wsum[4];
    int t = threadIdx.x;   // 256
    int v = (t < NCB) ? ccnt[t] : 0;
    int lane = t & 63, wid = t >> 6;
    int x = v;
    #pragma unroll
    for (int o = 1; o < 64; o <<= 1) { int y = __shfl_up(x, o); if (lane >= o) x += y; }
    if (lane == 63) wsum[wid] = x;
    __syncthreads();
    if (t == 0) {
        int s = 0;
        #pragma unroll
        for (int k = 0; k < 4; ++k) { int tmp = wsum[k]; wsum[k] = s; s += tmp; }
    }
    __syncthreads();
    int ex = x - v + wsum[wid];
    if (t < NCB) { cstart[t] = ex; ccur[t] = ex; }
    if (t == 0) { cstart[NCB] = E; rstart[NT] = E; }
}

// ---------------- phase 1: bin edges into coarse buckets, block-owned runs ----------------
// packed: x = (rl9 << 17) | col, y = val bits
__global__ void coarse_bin_kernel(const int* __restrict__ rows, const int* __restrict__ cols,
                                  const float* __restrict__ vals, int E,
                                  int* __restrict__ ccur, int2* __restrict__ bedges) {
    __shared__ int h[NCB];
    __shared__ int cur[NCB];
    int t = threadIdx.x;
    if (t < NCB) h[t] = 0;
    __syncthreads();
    int base = blockIdx.x * TILE;
    for (int it = 0; it < TILE / 256; ++it) {
        int e = base + it * 256 + t;
        if (e < E) atomicAdd(&h[rows[e] >> 9], 1);
    }
    __syncthreads();
    if (t < NCB) {
        int c = h[t];
        cur[t] = c ? atomicAdd(&ccur[t], c) : 0;   // one global atomic per (block,bucket)
    }
    __syncthreads();
    for (int it = 0; it < TILE / 256; ++it) {
        int e = base + it * 256 + t;
        if (e < E) {
            int r = rows[e];
            int cb = r >> 9;
            int p = atomicAdd(&cur[cb], 1);
            bedges[p] = make_int2(((r & 511) << 17) | cols[e], __float_as_int(vals[e]));
        }
    }
}

// ---------------- phase 2: per-coarse-bucket row sort + CSR offset build ----------------
__global__ void fine_sort_kernel(const int* __restrict__ cstart, const int2* __restrict__ bedges,
                                 int2* __restrict__ edges, int* __restrict__ rstart) {
    __shared__ int h[CBR];
    __shared__ int lcur[CBR];
    __shared__ int wsum[8];
    int b = blockIdx.x;
    int t = threadIdx.x;   // 512
    int r0 = b * CBR;
    int nrows = min(CBR, NT - r0);
    h[t] = 0;
    __syncthreads();
    int e0 = cstart[b];
    int e1 = cstart[b + 1];
    for (int k = e0 + t; k < e1; k += 512) atomicAdd(&h[bedges[k].x >> 17], 1);
    __syncthreads();
    // exclusive scan of h[512]
    int v = h[t];
    int lane = t & 63, wid = t >> 6;
    int x = v;
    #pragma unroll
    for (int o = 1; o < 64; o <<= 1) { int y = __shfl_up(x, o); if (lane >= o) x += y; }
    if (lane == 63) wsum[wid] = x;
    __syncthreads();
    if (t == 0) {
        int s = 0;
        #pragma unroll
        for (int k = 0; k < 8; ++k) { int tmp = wsum[k]; wsum[k] = s; s += tmp; }
    }
    __syncthreads();
    int gpos = e0 + x - v + wsum[wid];
    if (t < nrows) rstart[r0 + t] = gpos;
    lcur[t] = gpos;
    __syncthreads();
    for (int k = e0 + t; k < e1; k += 512) {
        int2 ed = bedges[k];
        int rl = ed.x >> 17;
        int p = atomicAdd(&lcur[rl], 1);
        edges[p] = make_int2(ed.x & 0x1FFFF, ed.y);
    }
}

// ---------------- fp32 concat -> fp16 ----------------
__global__ void concat_half_kernel(const float* __restrict__ u, const float* __restrict__ it,
                                   __half* __restrict__ x0) {
    long long i = (long long)blockIdx.x * 256 + threadIdx.x;
    if (i >= ND) return;
    long long half1 = (long long)NU * DD;
    float v = (i < half1) ? u[i] : it[i - half1];
    x0[i] = (__half)v;
}

// ---------------- SpMM: wave per row, 4 edges in flight (16 lanes/row-gather) ----------------
__global__ void spmm_csr_kernel(const int* __restrict__ rstart, const int2* __restrict__ edges,
                                const __half* __restrict__ x, const float* __restrict__ noise,
                                __half* __restrict__ y) {
    int gid = blockIdx.x * blockDim.x + threadIdx.x;
    int row = gid >> 6;
    int lane = gid & 63;
    if (row >= NT) return;
    int group = lane >> 4;     // 0..3: which edge of the chunk-of-4
    int sub = lane & 15;       // dims sub*4 .. sub*4+3
    int s0 = rstart[row];
    int s1 = rstart[row + 1];
    const ushort* xs = (const ushort*)x;
    float4 acc = make_float4(0.f, 0.f, 0.f, 0.f);
    for (int base = s0; base < s1; base += 64) {
        int k = base + lane;
        int2 ed = (k < s1) ? edges[k] : make_int2(0, 0);
        int lim = min(64, s1 - base);
        int nj = (lim + 3) >> 2;
        for (int j = 0; j < nj; ++j) {
            int ei = (j << 2) + group;
            int c = __shfl(ed.x, ei);
            float v = __int_as_float(__shfl(ed.y, ei));
            if (ei < lim) {
                uint2 q = *(const uint2*)(xs + ((size_t)c << 6) + (sub << 2));
                __half2 a01 = *reinterpret_cast<__half2*>(&q.x);
                __half2 a23 = *reinterpret_cast<__half2*>(&q.y);
                float2 f01 = __half22float2(a01);
                float2 f23 = __half22float2(a23);
                acc.x += v * f01.x; acc.y += v * f01.y;
                acc.z += v * f23.x; acc.w += v * f23.y;
            }
        }
    }
    // reduce across the 4 groups (lane bits 4,5)
    #pragma unroll
    for (int o = 16; o < 64; o <<= 1) {
        acc.x += __shfl_xor(acc.x, o);
        acc.y += __shfl_xor(acc.y, o);
        acc.z += __shfl_xor(acc.z, o);
        acc.w += __shfl_xor(acc.w, o);
    }
    // perturb: + sign(acc) * (noise/||noise||) * EPS
    float4 n4 = ((const float4*)noise)[(size_t)row * 16 + sub];
    float s = n4.x * n4.x + n4.y * n4.y + n4.z * n4.z + n4.w * n4.w;
    #pragma unroll
    for (int o = 1; o < 16; o <<= 1) s += __shfl_xor(s, o);
    float inv = EPS_ / fmaxf(sqrtf(s), 1e-12f);
    float rx = acc.x + ((acc.x > 0.f) ? 1.f : ((acc.x < 0.f) ? -1.f : 0.f)) * n4.x * inv;
    float ry = acc.y + ((acc.y > 0.f) ? 1.f : ((acc.y < 0.f) ? -1.f : 0.f)) * n4.y * inv;
    float rz = acc.z + ((acc.z > 0.f) ? 1.f : ((acc.z < 0.f) ? -1.f : 0.f)) * n4.z * inv;
    float rw = acc.w + ((acc.w > 0.f) ? 1.f : ((acc.w < 0.f) ? -1.f : 0.f)) * n4.w * inv;
    if (group == 0) {
        __half2 o01 = __floats2half2_rn(rx, ry);
        __half2 o23 = __floats2half2_rn(rz, rw);
        uint2 q;
        q.x = *reinterpret_cast<uint*>(&o01);
        q.y = *reinterpret_cast<uint*>(&o23);
        *(uint2*)((ushort*)y + ((size_t)row << 6) + (sub << 2)) = q;
    }
}

// ---------------- unique via flags ----------------
__global__ void unique_kernel(const int* __restrict__ in, int n, int* __restrict__ flags,
                              int* __restrict__ list, int* __restrict__ count) {
    int t = blockIdx.x * blockDim.x + threadIdx.x;
    if (t >= n) return;
    int u = in[t];
    if (atomicExch(&flags[u], 1) == 0) {
        int p = atomicAdd(count, 1);
        list[p] = u;
    }
}

// ---------------- gather + normalize v1 (light_out) & v2 (emb_cl), pos score ----------------
__global__ void gather_cl_kernel(const int* __restrict__ list, const int* __restrict__ count,
                                 int baseRow,
                                 const __half* __restrict__ A, const __half* __restrict__ B,
                                 const __half* __restrict__ C,
                                 float* __restrict__ V1, float* __restrict__ V2,
                                 float* __restrict__ posv) {
    int gid = blockIdx.x * blockDim.x + threadIdx.x;
    int s = gid >> 6;
    int lane = gid & 63;
    if (s >= NBATCH) return;
    int cnt = *count;
    float v1 = 0.f, v2 = 0.f;
    if (s < cnt) {
        size_t r = (size_t)(baseRow + list[s]) * DD + lane;
        v1 = ((float)A[r] + (float)B[r] + (float)C[r]) * (1.f / 3.f);
        v2 = (float)B[r];
    }
    float s1 = v1 * v1, s2 = v2 * v2;
    #pragma unroll
    for (int o = 32; o > 0; o >>= 1) { s1 += __shfl_xor(s1, o); s2 += __shfl_xor(s2, o); }
    v1 = v1 / fmaxf(sqrtf(s1), 1e-12f);
    v2 = v2 / fmaxf(sqrtf(s2), 1e-12f);
    V1[s * DD + lane] = v1;
    V2[s * DD + lane] = v2;
    float d = v1 * v2;
    #pragma unroll
    for (int o = 32; o > 0; o >>= 1) d += __shfl_xor(d, o);
    if (lane == 0) posv[s] = __expf(d * INV_TEMP);
}

// ---------------- ttl: 64x64 output tile per block, 4x4 register tiling ----------------
__global__ void ttl_kernel(const float* __restrict__ V1, const float* __restrict__ V2,
                           const int* __restrict__ count, float* __restrict__ ttl) {
    __shared__ float sA[64 * 68];
    __shared__ float sB[64 * 68];
    __shared__ float red[64];
    int cnt = *count;
    int i0 = blockIdx.x * 64;
    int j0 = blockIdx.y * 64;
    if (j0 >= cnt) return;
    int t = threadIdx.x;
    for (int k = t; k < 64 * 64; k += 256) {
        int r = k >> 6, d = k & 63;
        sA[d * 68 + r] = V1[(i0 + r) * DD + d];
        sB[d * 68 + r] = V2[(j0 + r) * DD + d];
    }
    if (t < 64) red[t] = 0.f;
    __syncthreads();
    int tx = t & 15;
    int ty = t >> 4;
    float acc[4][4] = {{0.f}};
    for (int d = 0; d < 64; ++d) {
        float4 a = *(const float4*)&sA[d * 68 + ty * 4];
        float4 b = *(const float4*)&sB[d * 68 + tx * 4];
        acc[0][0] += a.x * b.x; acc[0][1] += a.x * b.y; acc[0][2] += a.x * b.z; acc[0][3] += a.x * b.w;
        acc[1][0] += a.y * b.x; acc[1][1] += a.y * b.y; acc[1][2] += a.y * b.z; acc[1][3] += a.y * b.w;
        acc[2][0] += a.z * b.x; acc[2][1] += a.z * b.y; acc[2][2] += a.z * b.z; acc[2][3] += a.z * b.w;
        acc[3][0] += a.w * b.x; acc[3][1] += a.w * b.y; acc[3][2] += a.w * b.z; acc[3][3] += a.w * b.w;
    }
    #pragma unroll
    for (int ii = 0; ii < 4; ++ii) {
        float rs = 0.f;
        #pragma unroll
        for (int jj = 0; jj < 4; ++jj) {
            int j = j0 + tx * 4 + jj;
            if (j < cnt) rs += __expf(acc[ii][jj] * INV_TEMP);
        }
        atomicAdd(&red[ty * 4 + ii], rs);
    }
    __syncthreads();
    if (t < 64) atomicAdd(&ttl[i0 + t], red[t]);
}

// ---------------- cl partial ----------------
__global__ void cl_reduce_kernel(const float* __restrict__ posv, const float* __restrict__ ttl,
                                 const int* __restrict__ count, float* __restrict__ acc) {
    int t = blockIdx.x * blockDim.x + threadIdx.x;
    if (t >= NBATCH) return;
    int cnt = *count;
    float term = 0.f;
    if (t < cnt) term = -logf(posv[t] / ttl[t] + 1e-5f);
    #pragma unroll
    for (int o = 32; o > 0; o >>= 1) term += __shfl_xor(term, o);
    if ((t & 63) == 0) atomicAdd(acc, term);
}

// ---------------- BPR + reg ----------------
__global__ void bpr_kernel(const int* __restrict__ users, const int* __restrict__ pos,
                           const int* __restrict__ neg,
                           const __half* __restrict__ A, const __half* __restrict__ B,
                           const __half* __restrict__ C,
                           const float* __restrict__ user_emb, const float* __restrict__ item_emb,
                           float* __restrict__ mf_acc, float* __restrict__ reg_acc) {
    int gid = blockIdx.x * blockDim.x + threadIdx.x;
    int b = gid >> 6;
    int lane = gid & 63;
    if (b >= NBATCH) return;
    int u = users[b], p = pos[b], n = neg[b];
    size_t ru = (size_t)u * DD + lane;
    size_t rp = (size_t)(NU + p) * DD + lane;
    size_t rn = (size_t)(NU + n) * DD + lane;
    float ue = ((float)A[ru] + (float)B[ru] + (float)C[ru]) * (1.f / 3.f);
    float pe = ((float)A[rp] + (float)B[rp] + (float)C[rp]) * (1.f / 3.f);
    float ne = ((float)A[rn] + (float)B[rn] + (float)C[rn]) * (1.f / 3.f);
    float su = ue * ue, sp = pe * pe, sn = ne * ne, dp = ue * pe, dn = ue * ne;
    float u0 = user_emb[(size_t)u * DD + lane];
    float p0 = item_emb[(size_t)p * DD + lane];
    float n0 = item_emb[(size_t)n * DD + lane];
    float rg = u0 * u0 + p0 * p0 + n0 * n0;
    #pragma unroll
    for (int o = 32; o > 0; o >>= 1) {
        su += __shfl_xor(su, o); sp += __shfl_xor(sp, o); sn += __shfl_xor(sn, o);
        dp += __shfl_xor(dp, o); dn += __shfl_xor(dn, o); rg += __shfl_xor(rg, o);
    }
    if (lane == 0) {
        float nu = fmaxf(sqrtf(su), 1e-12f);
        float np_ = fmaxf(sqrtf(sp), 1e-12f);
        float nn_ = fmaxf(sqrtf(sn), 1e-12f);
        float ps = dp / (nu * np_);
        float ns = dn / (nu * nn_);
        float xx = ps - ns;
        float sig = 1.f / (1.f + __expf(-xx));
        atomicAdd(mf_acc, logf(sig + 1e-6f));
        atomicAdd(reg_acc, rg);
    }
}

// ---------------- finalize ----------------
__global__ void finalize_kernel(const float* __restrict__ mf_acc, const float* __restrict__ reg_acc,
                                const float* __restrict__ clu, const float* __restrict__ cli,
                                const int* __restrict__ cntu, const int* __restrict__ cnti,
                                float* __restrict__ out) {
    if (threadIdx.x == 0 && blockIdx.x == 0) {
        out[0] = -(*mf_acc) / (float)NBATCH;
        out[1] = 0.2f * ((*clu) / (float)(*cntu) + (*cli) / (float)(*cnti));
        out[2] = 1e-4f * 0.5f * (*reg_acc) / (float)NBATCH;
    }
}

extern "C" void kernel_launch(void* const* d_in, const int* in_sizes, int n_in,
                              void* d_out, int out_size, void* d_ws, size_t ws_size,
                              hipStream_t stream) {
    const int*   users     = (const int*)d_in[0];
    const int*   pos_items = (const int*)d_in[1];
    const int*   neg_items = (const int*)d_in[2];
    const float* user_emb  = (const float*)d_in[3];
    const float* item_emb  = (const float*)d_in[4];
    const int*   rows      = (const int*)d_in[5];
    const int*   cols      = (const int*)d_in[6];
    const float* vals      = (const float*)d_in[7];
    const float* noise     = (const float*)d_in[8];
    float* out = (float*)d_out;
    const int E = in_sizes[5];

    // ---- workspace carve (256B aligned) ----
    char* w = (char*)d_ws;
    size_t off = 0;
    auto carve = [&](size_t bytes) { char* p = w + off; off = (off + bytes + 255) & ~(size_t)255; return p; };
    __half* bufX = (__half*)carve(ND * 2);
    __half* bufA = (__half*)carve(ND * 2);
    __half* bufB = (__half*)carve(ND * 2);
    __half* bufC = (__half*)carve(ND * 2);
    int2*  bedges  = (int2*)carve((size_t)E * 8);
    int2*  edges   = (int2*)carve((size_t)E * 8);
    int*   rstart  = (int*)carve((NT + 1) * 4);
    int*   ccnt    = (int*)carve(NCB * 4);
    int*   cstart  = (int*)carve((NCB + 1) * 4);
    int*   ccur    = (int*)carve(NCB * 4);
    int* flags_u = (int*)carve(NU * 4);
    int* flags_i = (int*)carve(NI * 4);
    int* ulist   = (int*)carve(NBATCH * 4);
    int* ilist   = (int*)carve(NBATCH * 4);
    int* cnts    = (int*)carve(2 * 4);
    float* V1u = (float*)carve((size_t)NBATCH * DD * 4);
    float* V2u = (float*)carve((size_t)NBATCH * DD * 4);
    float* V1i = (float*)carve((size_t)NBATCH * DD * 4);
    float* V2i = (float*)carve((size_t)NBATCH * DD * 4);
    float* pos_u = (float*)carve(NBATCH * 4);
    float* pos_i = (float*)carve(NBATCH * 4);
    float* ttl_u = (float*)carve(NBATCH * 4);
    float* ttl_i = (float*)carve(NBATCH * 4);
    float* accum = (float*)carve(4 * 4);

    // ---- zero small scratch ----
    hipMemsetAsync(ccnt, 0, NCB * 4, stream);
    hipMemsetAsync(flags_u, 0, NU * 4, stream);
    hipMemsetAsync(flags_i, 0, NI * 4, stream);
    hipMemsetAsync(cnts, 0, 2 * 4, stream);
    hipMemsetAsync(accum, 0, 4 * 4, stream);
    hipMemsetAsync(ttl_u, 0, NBATCH * 4, stream);
    hipMemsetAsync(ttl_i, 0, NBATCH * 4, stream);

    const int nTiles = (E + TILE - 1) / TILE;             // 391
    const int rowBlocks  = (NT * DD + 255) / 256;
    const int slotBlocks = (NBATCH * DD + 255) / 256;
    const int ndBlocks   = (int)((ND + 255) / 256);

    // ---- edge sort: coarse hist -> scan -> coarse bin -> fine sort (builds rstart too) ----
    coarse_hist_kernel<<<nTiles, 256, 0, stream>>>(rows, E, ccnt);
    coarse_scan_kernel<<<1, 256, 0, stream>>>(ccnt, cstart, ccur, rstart, E);
    coarse_bin_kernel<<<nTiles, 256, 0, stream>>>(rows, cols, vals, E, ccur, bedges);
    fine_sort_kernel<<<NCB, 512, 0, stream>>>(cstart, bedges, edges, rstart);

    // ---- fp16 input concat ----
    concat_half_kernel<<<ndBlocks, 256, 0, stream>>>(user_emb, item_emb, bufX);

    // ---- 3 propagation layers (perturb fused) ----
    spmm_csr_kernel<<<rowBlocks, 256, 0, stream>>>(rstart, edges, bufX, noise + 0 * ND, bufB);
    spmm_csr_kernel<<<rowBlocks, 256, 0, stream>>>(rstart, edges, bufB, noise + 1 * ND, bufC);
    spmm_csr_kernel<<<rowBlocks, 256, 0, stream>>>(rstart, edges, bufC, noise + 2 * ND, bufA);

    // ---- unique ----
    unique_kernel<<<(NBATCH + 255) / 256, 256, 0, stream>>>(users, NBATCH, flags_u, ulist, &cnts[0]);
    unique_kernel<<<(NBATCH + 255) / 256, 256, 0, stream>>>(pos_items, NBATCH, flags_i, ilist, &cnts[1]);

    // ---- gather + normalize + pos scores ----
    gather_cl_kernel<<<slotBlocks, 256, 0, stream>>>(ulist, &cnts[0], 0,  bufA, bufB, bufC, V1u, V2u, pos_u);
    gather_cl_kernel<<<slotBlocks, 256, 0, stream>>>(ilist, &cnts[1], NU, bufA, bufB, bufC, V1i, V2i, pos_i);

    // ---- ttl sums ----
    dim3 tgrid(NBATCH / 64, NBATCH / 64);
    ttl_kernel<<<tgrid, 256, 0, stream>>>(V1u, V2u, &cnts[0], ttl_u);
    ttl_kernel<<<tgrid, 256, 0, stream>>>(V1i, V2i, &cnts[1], ttl_i);

    // ---- cl partial sums ----
    cl_reduce_kernel<<<(NBATCH + 255) / 256, 256, 0, stream>>>(pos_u, ttl_u, &cnts[0], &accum[2]);
    cl_reduce_kernel<<<(NBATCH + 255) / 256, 256, 0, stream>>>(pos_i, ttl_i, &cnts[1], &accum[3]);

    // ---- BPR + reg ----
    bpr_kernel<<<slotBlocks, 256, 0, stream>>>(users, pos_items, neg_items, bufA, bufB, bufC,
                                               user_emb, item_emb, &accum[0], &accum[1]);

    // ---- finalize ----
    finalize_kernel<<<1, 64, 0, stream>>>(&accum[0], &accum[1], &accum[2], &accum[3],
                                          &cnts[0], &cnts[1], out);
}

// Round 6
// 696.978 us; speedup vs baseline: 6.7871x; 1.1434x over previous
//
#include <hip/hip_runtime.h>
#include <hip/hip_fp16.h>
#include <math.h>

#define NU 50000
#define NI 50000
#define NT 100000
#define DD 64
#define NBATCH 4096
#define INV_TEMP 5.0f
#define EPS_ 0.2f

#define CBR 512                            // rows per coarse bucket
#define NCB ((NT + CBR - 1) / CBR)         // 196
#define TILE 8192                          // edges per phase-1 block
#define ND ((long long)NT * DD)            // 6,400,000
#define BPR_BLOCKS (NBATCH / 4)            // 1024 partials

// ---------------- coarse histogram: 196 buckets, LDS-aggregated ----------------
__global__ void coarse_hist_kernel(const int* __restrict__ rows, int E, int* __restrict__ ccnt) {
    __shared__ int h[NCB];
    int t = threadIdx.x;
    if (t < NCB) h[t] = 0;
    __syncthreads();
    int base = blockIdx.x * TILE;
    for (int it = 0; it < TILE / 256; ++it) {
        int e = base + it * 256 + t;
        if (e < E) atomicAdd(&h[rows[e] >> 9], 1);
    }
    __syncthreads();
    if (t < NCB && h[t]) atomicAdd(&ccnt[t], h[t]);
}

// ---------------- coarse scan: 196 entries -> cstart[197], ccur; set rstart[NT] ----------------
__global__ void coarse_scan_kernel(const int* __restrict__ ccnt, int* __restrict__ cstart,
                                   int* __restrict__ ccur, int* __restrict__ rstart, int E) {
    __shared__ int wsum[4];
    int t = threadIdx.x;   // 256
    int v = (t < NCB) ? ccnt[t] : 0;
    int lane = t & 63, wid = t >> 6;
    int x = v;
    #pragma unroll
    for (int o = 1; o < 64; o <<= 1) { int y = __shfl_up(x, o); if (lane >= o) x += y; }
    if (lane == 63) wsum[wid] = x;
    __syncthreads();
    if (t == 0) {
        int s = 0;
        #pragma unroll
        for (int k = 0; k < 4; ++k) { int tmp = wsum[k]; wsum[k] = s; s += tmp; }
    }
    __syncthreads();
    int ex = x - v + wsum[wid];
    if (t < NCB) { cstart[t] = ex; ccur[t] = ex; }
    if (t == 0) { cstart[NCB] = E; rstart[NT] = E; }
}

// ---------------- phase 1: bin edges into coarse buckets, block-owned runs ----------------
__global__ void coarse_bin_kernel(const int* __restrict__ rows, const int* __restrict__ cols,
                                  const float* __restrict__ vals, int E,
                                  int* __restrict__ ccur, int2* __restrict__ bedges) {
    __shared__ int h[NCB];
    __shared__ int cur[NCB];
    int t = threadIdx.x;
    if (t < NCB) h[t] = 0;
    __syncthreads();
    int base = blockIdx.x * TILE;
    for (int it = 0; it < TILE / 256; ++it) {
        int e = base + it * 256 + t;
        if (e < E) atomicAdd(&h[rows[e] >> 9], 1);
    }
    __syncthreads();
    if (t < NCB) {
        int c = h[t];
        cur[t] = c ? atomicAdd(&ccur[t], c) : 0;   // one global atomic per (block,bucket)
    }
    __syncthreads();
    for (int it = 0; it < TILE / 256; ++it) {
        int e = base + it * 256 + t;
        if (e < E) {
            int r = rows[e];
            int cb = r >> 9;
            int p = atomicAdd(&cur[cb], 1);
            bedges[p] = make_int2(((r & 511) << 17) | cols[e], __float_as_int(vals[e]));
        }
    }
}

// ---------------- phase 2: per-coarse-bucket row sort + CSR offset build ----------------
__global__ void fine_sort_kernel(const int* __restrict__ cstart, const int2* __restrict__ bedges,
                                 int2* __restrict__ edges, int* __restrict__ rstart) {
    __shared__ int h[CBR];
    __shared__ int lcur[CBR];
    __shared__ int wsum[8];
    int b = blockIdx.x;
    int t = threadIdx.x;   // 512
    int r0 = b * CBR;
    int nrows = min(CBR, NT - r0);
    h[t] = 0;
    __syncthreads();
    int e0 = cstart[b];
    int e1 = cstart[b + 1];
    for (int k = e0 + t; k < e1; k += 512) atomicAdd(&h[bedges[k].x >> 17], 1);
    __syncthreads();
    int v = h[t];
    int lane = t & 63, wid = t >> 6;
    int x = v;
    #pragma unroll
    for (int o = 1; o < 64; o <<= 1) { int y = __shfl_up(x, o); if (lane >= o) x += y; }
    if (lane == 63) wsum[wid] = x;
    __syncthreads();
    if (t == 0) {
        int s = 0;
        #pragma unroll
        for (int k = 0; k < 8; ++k) { int tmp = wsum[k]; wsum[k] = s; s += tmp; }
    }
    __syncthreads();
    int gpos = e0 + x - v + wsum[wid];
    if (t < nrows) rstart[r0 + t] = gpos;
    lcur[t] = gpos;
    __syncthreads();
    for (int k = e0 + t; k < e1; k += 512) {
        int2 ed = bedges[k];
        int rl = ed.x >> 17;
        int p = atomicAdd(&lcur[rl], 1);
        edges[p] = make_int2(ed.x & 0x1FFFF, ed.y);
    }
}

// ---------------- fp32 concat -> fp16 ----------------
__global__ void concat_half_kernel(const float* __restrict__ u, const float* __restrict__ it,
                                   __half* __restrict__ x0) {
    long long i = (long long)blockIdx.x * 256 + threadIdx.x;
    if (i >= ND) return;
    long long half1 = (long long)NU * DD;
    float v = (i < half1) ? u[i] : it[i - half1];
    x0[i] = (__half)v;
}

// ---------------- SpMM: wave per row, 4 edges in flight (16 lanes/row-gather) ----------------
__global__ void spmm_csr_kernel(const int* __restrict__ rstart, const int2* __restrict__ edges,
                                const __half* __restrict__ x, const float* __restrict__ noise,
                                __half* __restrict__ y) {
    int gid = blockIdx.x * blockDim.x + threadIdx.x;
    int row = gid >> 6;
    int lane = gid & 63;
    if (row >= NT) return;
    int group = lane >> 4;
    int sub = lane & 15;
    int s0 = rstart[row];
    int s1 = rstart[row + 1];
    const ushort* xs = (const ushort*)x;
    float4 acc = make_float4(0.f, 0.f, 0.f, 0.f);
    for (int base = s0; base < s1; base += 64) {
        int k = base + lane;
        int2 ed = (k < s1) ? edges[k] : make_int2(0, 0);
        int lim = min(64, s1 - base);
        int nj = (lim + 3) >> 2;
        for (int j = 0; j < nj; ++j) {
            int ei = (j << 2) + group;
            int c = __shfl(ed.x, ei);
            float v = __int_as_float(__shfl(ed.y, ei));
            if (ei < lim) {
                uint2 q = *(const uint2*)(xs + ((size_t)c << 6) + (sub << 2));
                __half2 a01 = *reinterpret_cast<__half2*>(&q.x);
                __half2 a23 = *reinterpret_cast<__half2*>(&q.y);
                float2 f01 = __half22float2(a01);
                float2 f23 = __half22float2(a23);
                acc.x += v * f01.x; acc.y += v * f01.y;
                acc.z += v * f23.x; acc.w += v * f23.y;
            }
        }
    }
    #pragma unroll
    for (int o = 16; o < 64; o <<= 1) {
        acc.x += __shfl_xor(acc.x, o);
        acc.y += __shfl_xor(acc.y, o);
        acc.z += __shfl_xor(acc.z, o);
        acc.w += __shfl_xor(acc.w, o);
    }
    float4 n4 = ((const float4*)noise)[(size_t)row * 16 + sub];
    float s = n4.x * n4.x + n4.y * n4.y + n4.z * n4.z + n4.w * n4.w;
    #pragma unroll
    for (int o = 1; o < 16; o <<= 1) s += __shfl_xor(s, o);
    float inv = EPS_ / fmaxf(sqrtf(s), 1e-12f);
    float rx = acc.x + ((acc.x > 0.f) ? 1.f : ((acc.x < 0.f) ? -1.f : 0.f)) * n4.x * inv;
    float ry = acc.y + ((acc.y > 0.f) ? 1.f : ((acc.y < 0.f) ? -1.f : 0.f)) * n4.y * inv;
    float rz = acc.z + ((acc.z > 0.f) ? 1.f : ((acc.z < 0.f) ? -1.f : 0.f)) * n4.z * inv;
    float rw = acc.w + ((acc.w > 0.f) ? 1.f : ((acc.w < 0.f) ? -1.f : 0.f)) * n4.w * inv;
    if (group == 0) {
        __half2 o01 = __floats2half2_rn(rx, ry);
        __half2 o23 = __floats2half2_rn(rz, rw);
        uint2 q;
        q.x = *reinterpret_cast<uint*>(&o01);
        q.y = *reinterpret_cast<uint*>(&o23);
        *(uint2*)((ushort*)y + ((size_t)row << 6) + (sub << 2)) = q;
    }
}

// ---------------- unique via flags, wave-aggregated counter ----------------
__global__ void unique_kernel(const int* __restrict__ in, int n, int* __restrict__ flags,
                              int* __restrict__ list, int* __restrict__ count) {
    int t = blockIdx.x * blockDim.x + threadIdx.x;
    bool isnew = false;
    int u = 0;
    if (t < n) {
        u = in[t];
        isnew = (atomicExch(&flags[u], 1) == 0);
    }
    unsigned long long mask = __ballot(isnew);
    int nnew = __popcll(mask);
    int lane = threadIdx.x & 63;
    int base = 0;
    if (nnew) {
        if (lane == __ffsll((long long)mask) - 1) base = atomicAdd(count, nnew);
        base = __shfl(base, __ffsll((long long)mask) - 1);
        if (isnew) {
            int rank = __popcll(mask & ((1ull << lane) - 1ull));
            list[base + rank] = u;
        }
    }
}

// ---------------- gather + normalize v1 (light_out) & v2 (emb_cl), pos score ----------------
__global__ void gather_cl_kernel(const int* __restrict__ list, const int* __restrict__ count,
                                 int baseRow,
                                 const __half* __restrict__ A, const __half* __restrict__ B,
                                 const __half* __restrict__ C,
                                 float* __restrict__ V1, float* __restrict__ V2,
                                 float* __restrict__ posv) {
    int gid = blockIdx.x * blockDim.x + threadIdx.x;
    int s = gid >> 6;
    int lane = gid & 63;
    if (s >= NBATCH) return;
    int cnt = *count;
    float v1 = 0.f, v2 = 0.f;
    if (s < cnt) {
        size_t r = (size_t)(baseRow + list[s]) * DD + lane;
        v1 = ((float)A[r] + (float)B[r] + (float)C[r]) * (1.f / 3.f);
        v2 = (float)B[r];
    }
    float s1 = v1 * v1, s2 = v2 * v2;
    #pragma unroll
    for (int o = 32; o > 0; o >>= 1) { s1 += __shfl_xor(s1, o); s2 += __shfl_xor(s2, o); }
    v1 = v1 / fmaxf(sqrtf(s1), 1e-12f);
    v2 = v2 / fmaxf(sqrtf(s2), 1e-12f);
    V1[s * DD + lane] = v1;
    V2[s * DD + lane] = v2;
    float d = v1 * v2;
    #pragma unroll
    for (int o = 32; o > 0; o >>= 1) d += __shfl_xor(d, o);
    if (lane == 0) posv[s] = __expf(d * INV_TEMP);
}

// ---------------- ttl: 64x64 output tile per block, 4x4 register tiling ----------------
__global__ void ttl_kernel(const float* __restrict__ V1, const float* __restrict__ V2,
                           const int* __restrict__ count, float* __restrict__ ttl) {
    __shared__ float sA[64 * 68];
    __shared__ float sB[64 * 68];
    __shared__ float red[64];
    int cnt = *count;
    int i0 = blockIdx.x * 64;
    int j0 = blockIdx.y * 64;
    if (j0 >= cnt) return;
    int t = threadIdx.x;
    for (int k = t; k < 64 * 64; k += 256) {
        int r = k >> 6, d = k & 63;
        sA[d * 68 + r] = V1[(i0 + r) * DD + d];
        sB[d * 68 + r] = V2[(j0 + r) * DD + d];
    }
    if (t < 64) red[t] = 0.f;
    __syncthreads();
    int tx = t & 15;
    int ty = t >> 4;
    float acc[4][4] = {{0.f}};
    for (int d = 0; d < 64; ++d) {
        float4 a = *(const float4*)&sA[d * 68 + ty * 4];
        float4 b = *(const float4*)&sB[d * 68 + tx * 4];
        acc[0][0] += a.x * b.x; acc[0][1] += a.x * b.y; acc[0][2] += a.x * b.z; acc[0][3] += a.x * b.w;
        acc[1][0] += a.y * b.x; acc[1][1] += a.y * b.y; acc[1][2] += a.y * b.z; acc[1][3] += a.y * b.w;
        acc[2][0] += a.z * b.x; acc[2][1] += a.z * b.y; acc[2][2] += a.z * b.z; acc[2][3] += a.z * b.w;
        acc[3][0] += a.w * b.x; acc[3][1] += a.w * b.y; acc[3][2] += a.w * b.z; acc[3][3] += a.w * b.w;
    }
    #pragma unroll
    for (int ii = 0; ii < 4; ++ii) {
        float rs = 0.f;
        #pragma unroll
        for (int jj = 0; jj < 4; ++jj) {
            int j = j0 + tx * 4 + jj;
            if (j < cnt) rs += __expf(acc[ii][jj] * INV_TEMP);
        }
        atomicAdd(&red[ty * 4 + ii], rs);
    }
    __syncthreads();
    if (t < 64) atomicAdd(&ttl[i0 + t], red[t]);
}

// ---------------- cl partial ----------------
__global__ void cl_reduce_kernel(const float* __restrict__ posv, const float* __restrict__ ttl,
                                 const int* __restrict__ count, float* __restrict__ acc) {
    int t = blockIdx.x * blockDim.x + threadIdx.x;
    if (t >= NBATCH) return;
    int cnt = *count;
    float term = 0.f;
    if (t < cnt) term = -logf(posv[t] / ttl[t] + 1e-5f);
    #pragma unroll
    for (int o = 32; o > 0; o >>= 1) term += __shfl_xor(term, o);
    if ((t & 63) == 0) atomicAdd(acc, term);
}

// ---------------- BPR + reg: block of 4 waves -> one float2 partial, NO global atomics ----------------
__global__ void bpr_kernel(const int* __restrict__ users, const int* __restrict__ pos,
                           const int* __restrict__ neg,
                           const __half* __restrict__ A, const __half* __restrict__ B,
                           const __half* __restrict__ C,
                           const float* __restrict__ user_emb, const float* __restrict__ item_emb,
                           float2* __restrict__ partials) {
    __shared__ float2 wp[4];
    int gid = blockIdx.x * blockDim.x + threadIdx.x;
    int b = gid >> 6;
    int lane = gid & 63;
    int wid = (threadIdx.x >> 6);
    float lg = 0.f, rgsum = 0.f;
    if (b < NBATCH) {
        int u = users[b], p = pos[b], n = neg[b];
        size_t ru = (size_t)u * DD + lane;
        size_t rp = (size_t)(NU + p) * DD + lane;
        size_t rn = (size_t)(NU + n) * DD + lane;
        float ue = ((float)A[ru] + (float)B[ru] + (float)C[ru]) * (1.f / 3.f);
        float pe = ((float)A[rp] + (float)B[rp] + (float)C[rp]) * (1.f / 3.f);
        float ne = ((float)A[rn] + (float)B[rn] + (float)C[rn]) * (1.f / 3.f);
        float su = ue * ue, sp = pe * pe, sn = ne * ne, dp = ue * pe, dn = ue * ne;
        float u0 = user_emb[(size_t)u * DD + lane];
        float p0 = item_emb[(size_t)p * DD + lane];
        float n0 = item_emb[(size_t)n * DD + lane];
        float rg = u0 * u0 + p0 * p0 + n0 * n0;
        #pragma unroll
        for (int o = 32; o > 0; o >>= 1) {
            su += __shfl_xor(su, o); sp += __shfl_xor(sp, o); sn += __shfl_xor(sn, o);
            dp += __shfl_xor(dp, o); dn += __shfl_xor(dn, o); rg += __shfl_xor(rg, o);
        }
        float nu = fmaxf(sqrtf(su), 1e-12f);
        float np_ = fmaxf(sqrtf(sp), 1e-12f);
        float nn_ = fmaxf(sqrtf(sn), 1e-12f);
        float ps = dp / (nu * np_);
        float ns = dn / (nu * nn_);
        float xx = ps - ns;
        float sig = 1.f / (1.f + __expf(-xx));
        lg = logf(sig + 1e-6f);
        rgsum = rg;
    }
    if (lane == 0) wp[wid] = make_float2(lg, rgsum);
    __syncthreads();
    if (threadIdx.x == 0) {
        float2 s = wp[0];
        s.x += wp[1].x + wp[2].x + wp[3].x;
        s.y += wp[1].y + wp[2].y + wp[3].y;
        partials[blockIdx.x] = s;
    }
}

// ---------------- finalize: reduce 1024 bpr partials + cl sums ----------------
__global__ void finalize_kernel(const float2* __restrict__ partials,
                                const float* __restrict__ clu, const float* __restrict__ cli,
                                const int* __restrict__ cntu, const int* __restrict__ cnti,
                                float* __restrict__ out) {
    __shared__ float2 wsum[16];
    int t = threadIdx.x;   // 1024
    float2 v = (t < BPR_BLOCKS) ? partials[t] : make_float2(0.f, 0.f);
    #pragma unroll
    for (int o = 32; o > 0; o >>= 1) { v.x += __shfl_xor(v.x, o); v.y += __shfl_xor(v.y, o); }
    if ((t & 63) == 0) wsum[t >> 6] = v;
    __syncthreads();
    if (t == 0) {
        float mf = 0.f, rg = 0.f;
        #pragma unroll
        for (int k = 0; k < 16; ++k) { mf += wsum[k].x; rg += wsum[k].y; }
        out[0] = -mf / (float)NBATCH;
        out[1] = 0.2f * ((*clu) / (float)(*cntu) + (*cli) / (float)(*cnti));
        out[2] = 1e-4f * 0.5f * rg / (float)NBATCH;
    }
}

extern "C" void kernel_launch(void* const* d_in, const int* in_sizes, int n_in,
                              void* d_out, int out_size, void* d_ws, size_t ws_size,
                              hipStream_t stream) {
    const int*   users     = (const int*)d_in[0];
    const int*   pos_items = (const int*)d_in[1];
    const int*   neg_items = (const int*)d_in[2];
    const float* user_emb  = (const float*)d_in[3];
    const float* item_emb  = (const float*)d_in[4];
    const int*   rows      = (const int*)d_in[5];
    const int*   cols      = (const int*)d_in[6];
    const float* vals      = (const float*)d_in[7];
    const float* noise     = (const float*)d_in[8];
    float* out = (float*)d_out;
    const int E = in_sizes[5];

    // ---- workspace carve (256B aligned) ----
    char* w = (char*)d_ws;
    size_t off = 0;
    auto carve = [&](size_t bytes) { char* p = w + off; off = (off + bytes + 255) & ~(size_t)255; return p; };
    __half* bufX = (__half*)carve(ND * 2);
    __half* bufA = (__half*)carve(ND * 2);
    __half* bufB = (__half*)carve(ND * 2);
    __half* bufC = (__half*)carve(ND * 2);
    int2*  bedges  = (int2*)carve((size_t)E * 8);
    int2*  edges   = (int2*)carve((size_t)E * 8);
    int*   rstart  = (int*)carve((NT + 1) * 4);
    int*   ccnt    = (int*)carve(NCB * 4);
    int*   cstart  = (int*)carve((NCB + 1) * 4);
    int*   ccur    = (int*)carve(NCB * 4);
    int* flags_u = (int*)carve(NU * 4);
    int* flags_i = (int*)carve(NI * 4);
    int* ulist   = (int*)carve(NBATCH * 4);
    int* ilist   = (int*)carve(NBATCH * 4);
    int* cnts    = (int*)carve(2 * 4);
    float* V1u = (float*)carve((size_t)NBATCH * DD * 4);
    float* V2u = (float*)carve((size_t)NBATCH * DD * 4);
    float* V1i = (float*)carve((size_t)NBATCH * DD * 4);
    float* V2i = (float*)carve((size_t)NBATCH * DD * 4);
    float* pos_u = (float*)carve(NBATCH * 4);
    float* pos_i = (float*)carve(NBATCH * 4);
    float* ttl_u = (float*)carve(NBATCH * 4);
    float* ttl_i = (float*)carve(NBATCH * 4);
    float2* bpr_part = (float2*)carve(BPR_BLOCKS * 8);
    float* accum = (float*)carve(4 * 4);          // [2]=clu, [3]=cli

    // ---- zero small scratch ----
    hipMemsetAsync(ccnt, 0, NCB * 4, stream);
    hipMemsetAsync(flags_u, 0, NU * 4, stream);
    hipMemsetAsync(flags_i, 0, NI * 4, stream);
    hipMemsetAsync(cnts, 0, 2 * 4, stream);
    hipMemsetAsync(accum, 0, 4 * 4, stream);
    hipMemsetAsync(ttl_u, 0, NBATCH * 4, stream);
    hipMemsetAsync(ttl_i, 0, NBATCH * 4, stream);

    const int nTiles = (E + TILE - 1) / TILE;
    const int rowBlocks  = (NT * DD + 255) / 256;
    const int slotBlocks = (NBATCH * DD + 255) / 256;
    const int ndBlocks   = (int)((ND + 255) / 256);

    // ---- edge sort: coarse hist -> scan -> coarse bin -> fine sort (builds rstart too) ----
    coarse_hist_kernel<<<nTiles, 256, 0, stream>>>(rows, E, ccnt);
    coarse_scan_kernel<<<1, 256, 0, stream>>>(ccnt, cstart, ccur, rstart, E);
    coarse_bin_kernel<<<nTiles, 256, 0, stream>>>(rows, cols, vals, E, ccur, bedges);
    fine_sort_kernel<<<NCB, 512, 0, stream>>>(cstart, bedges, edges, rstart);

    // ---- fp16 input concat ----
    concat_half_kernel<<<ndBlocks, 256, 0, stream>>>(user_emb, item_emb, bufX);

    // ---- 3 propagation layers (perturb fused) ----
    spmm_csr_kernel<<<rowBlocks, 256, 0, stream>>>(rstart, edges, bufX, noise + 0 * ND, bufB);
    spmm_csr_kernel<<<rowBlocks, 256, 0, stream>>>(rstart, edges, bufB, noise + 1 * ND, bufC);
    spmm_csr_kernel<<<rowBlocks, 256, 0, stream>>>(rstart, edges, bufC, noise + 2 * ND, bufA);

    // ---- unique ----
    unique_kernel<<<(NBATCH + 255) / 256, 256, 0, stream>>>(users, NBATCH, flags_u, ulist, &cnts[0]);
    unique_kernel<<<(NBATCH + 255) / 256, 256, 0, stream>>>(pos_items, NBATCH, flags_i, ilist, &cnts[1]);

    // ---- gather + normalize + pos scores ----
    gather_cl_kernel<<<slotBlocks, 256, 0, stream>>>(ulist, &cnts[0], 0,  bufA, bufB, bufC, V1u, V2u, pos_u);
    gather_cl_kernel<<<slotBlocks, 256, 0, stream>>>(ilist, &cnts[1], NU, bufA, bufB, bufC, V1i, V2i, pos_i);

    // ---- ttl sums ----
    dim3 tgrid(NBATCH / 64, NBATCH / 64);
    ttl_kernel<<<tgrid, 256, 0, stream>>>(V1u, V2u, &cnts[0], ttl_u);
    ttl_kernel<<<tgrid, 256, 0, stream>>>(V1i, V2i, &cnts[1], ttl_i);

    // ---- cl partial sums ----
    cl_reduce_kernel<<<(NBATCH + 255) / 256, 256, 0, stream>>>(pos_u, ttl_u, &cnts[0], &accum[2]);
    cl_reduce_kernel<<<(NBATCH + 255) / 256, 256, 0, stream>>>(pos_i, ttl_i, &cnts[1], &accum[3]);

    // ---- BPR + reg (two-stage, no global atomics) ----
    bpr_kernel<<<BPR_BLOCKS, 256, 0, stream>>>(users, pos_items, neg_items, bufA, bufB, bufC,
                                               user_emb, item_emb, bpr_part);

    // ---- finalize ----
    finalize_kernel<<<1, 1024, 0, stream>>>(bpr_part, &accum[2], &accum[3],
                                            &cnts[0], &cnts[1], out);
}

// Round 7
// 650.243 us; speedup vs baseline: 7.2749x; 1.0719x over previous
//
#include <hip/hip_runtime.h>
#include <hip/hip_fp16.h>
#include <math.h>

#define NU 50000
#define NI 50000
#define NT 100000
#define DD 64
#define NBATCH 4096
#define INV_TEMP 5.0f
#define EPS_ 0.2f

#define CBR 512                            // rows per coarse bucket
#define NCB ((NT + CBR - 1) / CBR)         // 196
#define TILE 8192                          // edges per phase-1 block
#define ND ((long long)NT * DD)            // 6,400,000
#define BPR_BLOCKS (NBATCH / 4)            // 1024 partials

// ---------------- coarse histogram: 196 buckets, LDS-aggregated ----------------
__global__ void coarse_hist_kernel(const int* __restrict__ rows, int E, int* __restrict__ ccnt) {
    __shared__ int h[NCB];
    int t = threadIdx.x;
    if (t < NCB) h[t] = 0;
    __syncthreads();
    int base = blockIdx.x * TILE;
    for (int it = 0; it < TILE / 256; ++it) {
        int e = base + it * 256 + t;
        if (e < E) atomicAdd(&h[rows[e] >> 9], 1);
    }
    __syncthreads();
    if (t < NCB && h[t]) atomicAdd(&ccnt[t], h[t]);
}

// ---------------- coarse scan: 196 entries -> cstart[197], ccur; set rstart[NT] ----------------
__global__ void coarse_scan_kernel(const int* __restrict__ ccnt, int* __restrict__ cstart,
                                   int* __restrict__ ccur, int* __restrict__ rstart, int E) {
    __shared__ int wsum[4];
    int t = threadIdx.x;   // 256
    int v = (t < NCB) ? ccnt[t] : 0;
    int lane = t & 63, wid = t >> 6;
    int x = v;
    #pragma unroll
    for (int o = 1; o < 64; o <<= 1) { int y = __shfl_up(x, o); if (lane >= o) x += y; }
    if (lane == 63) wsum[wid] = x;
    __syncthreads();
    if (t == 0) {
        int s = 0;
        #pragma unroll
        for (int k = 0; k < 4; ++k) { int tmp = wsum[k]; wsum[k] = s; s += tmp; }
    }
    __syncthreads();
    int ex = x - v + wsum[wid];
    if (t < NCB) { cstart[t] = ex; ccur[t] = ex; }
    if (t == 0) { cstart[NCB] = E; rstart[NT] = E; }
}

// ---------------- phase 1: bin edges into coarse buckets, block-owned runs ----------------
__global__ void coarse_bin_kernel(const int* __restrict__ rows, const int* __restrict__ cols,
                                  const float* __restrict__ vals, int E,
                                  int* __restrict__ ccur, int2* __restrict__ bedges) {
    __shared__ int h[NCB];
    __shared__ int cur[NCB];
    int t = threadIdx.x;
    if (t < NCB) h[t] = 0;
    __syncthreads();
    int base = blockIdx.x * TILE;
    for (int it = 0; it < TILE / 256; ++it) {
        int e = base + it * 256 + t;
        if (e < E) atomicAdd(&h[rows[e] >> 9], 1);
    }
    __syncthreads();
    if (t < NCB) {
        int c = h[t];
        cur[t] = c ? atomicAdd(&ccur[t], c) : 0;
    }
    __syncthreads();
    for (int it = 0; it < TILE / 256; ++it) {
        int e = base + it * 256 + t;
        if (e < E) {
            int r = rows[e];
            int cb = r >> 9;
            int p = atomicAdd(&cur[cb], 1);
            bedges[p] = make_int2(((r & 511) << 17) | cols[e], __float_as_int(vals[e]));
        }
    }
}

// ---------------- phase 2: per-coarse-bucket row sort + CSR offset build ----------------
__global__ void fine_sort_kernel(const int* __restrict__ cstart, const int2* __restrict__ bedges,
                                 int2* __restrict__ edges, int* __restrict__ rstart) {
    __shared__ int h[CBR];
    __shared__ int lcur[CBR];
    __shared__ int wsum[8];
    int b = blockIdx.x;
    int t = threadIdx.x;   // 512
    int r0 = b * CBR;
    int nrows = min(CBR, NT - r0);
    h[t] = 0;
    __syncthreads();
    int e0 = cstart[b];
    int e1 = cstart[b + 1];
    for (int k = e0 + t; k < e1; k += 512) atomicAdd(&h[bedges[k].x >> 17], 1);
    __syncthreads();
    int v = h[t];
    int lane = t & 63, wid = t >> 6;
    int x = v;
    #pragma unroll
    for (int o = 1; o < 64; o <<= 1) { int y = __shfl_up(x, o); if (lane >= o) x += y; }
    if (lane == 63) wsum[wid] = x;
    __syncthreads();
    if (t == 0) {
        int s = 0;
        #pragma unroll
        for (int k = 0; k < 8; ++k) { int tmp = wsum[k]; wsum[k] = s; s += tmp; }
    }
    __syncthreads();
    int gpos = e0 + x - v + wsum[wid];
    if (t < nrows) rstart[r0 + t] = gpos;
    lcur[t] = gpos;
    __syncthreads();
    for (int k = e0 + t; k < e1; k += 512) {
        int2 ed = bedges[k];
        int rl = ed.x >> 17;
        int p = atomicAdd(&lcur[rl], 1);
        edges[p] = make_int2(ed.x & 0x1FFFF, ed.y);
    }
}

// ---------------- fp32 concat -> fp16 (4 elems/thread) ----------------
__global__ void concat_half_kernel(const float* __restrict__ u, const float* __restrict__ it,
                                   __half* __restrict__ x0) {
    long long i = ((long long)blockIdx.x * 256 + threadIdx.x) * 4;
    if (i >= ND) return;
    long long half1 = (long long)NU * DD;
    float4 v = (i < half1) ? *(const float4*)(u + i) : *(const float4*)(it + (i - half1));
    __half2 h01 = __floats2half2_rn(v.x, v.y);
    __half2 h23 = __floats2half2_rn(v.z, v.w);
    uint2 q;
    q.x = *reinterpret_cast<uint*>(&h01);
    q.y = *reinterpret_cast<uint*>(&h23);
    *(uint2*)((ushort*)x0 + i) = q;
}

// ---------------- SpMM: wave per row, 8 edges in flight, branch-free ----------------
// Sentinel edges (col=0, val=0) make every unrolled iteration unconditional.
__global__ void spmm_csr_kernel(const int* __restrict__ rstart, const int2* __restrict__ edges,
                                const __half* __restrict__ x, const float* __restrict__ noise,
                                __half* __restrict__ y) {
    int gid = blockIdx.x * blockDim.x + threadIdx.x;
    int row = gid >> 6;
    int lane = gid & 63;
    if (row >= NT) return;
    int group = lane >> 3;     // 0..7: edge slot within each 8
    int sub = lane & 7;        // dims sub*8 .. sub*8+7
    int s0 = rstart[row];
    int s1 = rstart[row + 1];
    const ushort* xs = (const ushort*)x;
    float acc[8] = {0.f, 0.f, 0.f, 0.f, 0.f, 0.f, 0.f, 0.f};
    for (int base = s0; base < s1; base += 64) {
        int k = base + lane;
        int2 ed = (k < s1) ? edges[k] : make_int2(0, 0);   // sentinel: col 0, val 0
        #pragma unroll
        for (int j = 0; j < 8; ++j) {
            int ei = j * 8 + group;
            int c = __shfl(ed.x, ei);
            float v = __int_as_float(__shfl(ed.y, ei));
            uint4 q = *(const uint4*)(xs + ((size_t)c << 6) + (sub << 3));
            __half2 h0 = *reinterpret_cast<__half2*>(&q.x);
            __half2 h1 = *reinterpret_cast<__half2*>(&q.y);
            __half2 h2 = *reinterpret_cast<__half2*>(&q.z);
            __half2 h3 = *reinterpret_cast<__half2*>(&q.w);
            float2 f0 = __half22float2(h0);
            float2 f1 = __half22float2(h1);
            float2 f2 = __half22float2(h2);
            float2 f3 = __half22float2(h3);
            acc[0] += v * f0.x; acc[1] += v * f0.y;
            acc[2] += v * f1.x; acc[3] += v * f1.y;
            acc[4] += v * f2.x; acc[5] += v * f2.y;
            acc[6] += v * f3.x; acc[7] += v * f3.y;
        }
    }
    // reduce across the 8 groups (lane bits 3..5)
    #pragma unroll
    for (int o = 8; o < 64; o <<= 1) {
        #pragma unroll
        for (int d = 0; d < 8; ++d) acc[d] += __shfl_xor(acc[d], o);
    }
    // perturb
    const float4* nf = (const float4*)(noise + (size_t)row * DD);
    float4 na = nf[sub * 2];
    float4 nb = nf[sub * 2 + 1];
    float s = na.x * na.x + na.y * na.y + na.z * na.z + na.w * na.w
            + nb.x * nb.x + nb.y * nb.y + nb.z * nb.z + nb.w * nb.w;
    #pragma unroll
    for (int o = 1; o < 8; o <<= 1) s += __shfl_xor(s, o);
    float inv = EPS_ / fmaxf(sqrtf(s), 1e-12f);
    float nd_[8] = {na.x, na.y, na.z, na.w, nb.x, nb.y, nb.z, nb.w};
    float r[8];
    #pragma unroll
    for (int d = 0; d < 8; ++d) {
        float a = acc[d];
        float sg = (a > 0.f) ? 1.f : ((a < 0.f) ? -1.f : 0.f);
        r[d] = a + sg * nd_[d] * inv;
    }
    if (group == 0) {
        __half2 o0 = __floats2half2_rn(r[0], r[1]);
        __half2 o1 = __floats2half2_rn(r[2], r[3]);
        __half2 o2 = __floats2half2_rn(r[4], r[5]);
        __half2 o3 = __floats2half2_rn(r[6], r[7]);
        uint4 q;
        q.x = *reinterpret_cast<uint*>(&o0);
        q.y = *reinterpret_cast<uint*>(&o1);
        q.z = *reinterpret_cast<uint*>(&o2);
        q.w = *reinterpret_cast<uint*>(&o3);
        *(uint4*)((ushort*)y + ((size_t)row << 6) + (sub << 3)) = q;
    }
}

// ---------------- unique via flags, wave-aggregated; dual (y=0 users, y=1 items) ----------------
__global__ void unique_kernel(const int* __restrict__ users, const int* __restrict__ pos_items,
                              int* __restrict__ flags_u, int* __restrict__ flags_i,
                              int* __restrict__ ulist, int* __restrict__ ilist,
                              int* __restrict__ cnts) {
    int which = blockIdx.y;
    const int* in = which ? pos_items : users;
    int* flags = which ? flags_i : flags_u;
    int* list = which ? ilist : ulist;
    int* count = cnts + which;
    int t = blockIdx.x * blockDim.x + threadIdx.x;
    bool isnew = false;
    int u = 0;
    if (t < NBATCH) {
        u = in[t];
        isnew = (atomicExch(&flags[u], 1) == 0);
    }
    unsigned long long mask = __ballot(isnew);
    int nnew = __popcll(mask);
    int lane = threadIdx.x & 63;
    int base = 0;
    if (nnew) {
        int leader = __ffsll((long long)mask) - 1;
        if (lane == leader) base = atomicAdd(count, nnew);
        base = __shfl(base, leader);
        if (isnew) {
            int rank = __popcll(mask & ((1ull << lane) - 1ull));
            list[base + rank] = u;
        }
    }
}

// ---------------- gather + normalize; dual via blockIdx.y ----------------
__global__ void gather_cl_kernel(const int* __restrict__ ulist, const int* __restrict__ ilist,
                                 const int* __restrict__ cnts,
                                 const __half* __restrict__ A, const __half* __restrict__ B,
                                 const __half* __restrict__ C,
                                 float* __restrict__ V1, float* __restrict__ V2,
                                 float* __restrict__ posv) {
    int which = blockIdx.y;
    const int* list = which ? ilist : ulist;
    int baseRow = which ? NU : 0;
    int cnt = cnts[which];
    float* V1z = V1 + (size_t)which * NBATCH * DD;
    float* V2z = V2 + (size_t)which * NBATCH * DD;
    float* posz = posv + which * NBATCH;
    int gid = blockIdx.x * blockDim.x + threadIdx.x;
    int s = gid >> 6;
    int lane = gid & 63;
    if (s >= NBATCH) return;
    float v1 = 0.f, v2 = 0.f;
    if (s < cnt) {
        size_t r = (size_t)(baseRow + list[s]) * DD + lane;
        v1 = ((float)A[r] + (float)B[r] + (float)C[r]) * (1.f / 3.f);
        v2 = (float)B[r];
    }
    float s1 = v1 * v1, s2 = v2 * v2;
    #pragma unroll
    for (int o = 32; o > 0; o >>= 1) { s1 += __shfl_xor(s1, o); s2 += __shfl_xor(s2, o); }
    v1 = v1 / fmaxf(sqrtf(s1), 1e-12f);
    v2 = v2 / fmaxf(sqrtf(s2), 1e-12f);
    V1z[s * DD + lane] = v1;
    V2z[s * DD + lane] = v2;
    float d = v1 * v2;
    #pragma unroll
    for (int o = 32; o > 0; o >>= 1) d += __shfl_xor(d, o);
    if (lane == 0) posz[s] = __expf(d * INV_TEMP);
}

// ---------------- ttl: 64x64 tile, 4x4 register tiling; dual via blockIdx.z ----------------
__global__ void ttl_kernel(const float* __restrict__ V1, const float* __restrict__ V2,
                           const int* __restrict__ cnts, float* __restrict__ ttl) {
    __shared__ float sA[64 * 68];
    __shared__ float sB[64 * 68];
    __shared__ float red[64];
    int z = blockIdx.z;
    const float* V1z = V1 + (size_t)z * NBATCH * DD;
    const float* V2z = V2 + (size_t)z * NBATCH * DD;
    float* ttlz = ttl + z * NBATCH;
    int cnt = cnts[z];
    int i0 = blockIdx.x * 64;
    int j0 = blockIdx.y * 64;
    if (j0 >= cnt) return;
    int t = threadIdx.x;
    for (int k = t; k < 64 * 64; k += 256) {
        int r = k >> 6, d = k & 63;
        sA[d * 68 + r] = V1z[(i0 + r) * DD + d];
        sB[d * 68 + r] = V2z[(j0 + r) * DD + d];
    }
    if (t < 64) red[t] = 0.f;
    __syncthreads();
    int tx = t & 15;
    int ty = t >> 4;
    float acc[4][4] = {{0.f}};
    for (int d = 0; d < 64; ++d) {
        float4 a = *(const float4*)&sA[d * 68 + ty * 4];
        float4 b = *(const float4*)&sB[d * 68 + tx * 4];
        acc[0][0] += a.x * b.x; acc[0][1] += a.x * b.y; acc[0][2] += a.x * b.z; acc[0][3] += a.x * b.w;
        acc[1][0] += a.y * b.x; acc[1][1] += a.y * b.y; acc[1][2] += a.y * b.z; acc[1][3] += a.y * b.w;
        acc[2][0] += a.z * b.x; acc[2][1] += a.z * b.y; acc[2][2] += a.z * b.z; acc[2][3] += a.z * b.w;
        acc[3][0] += a.w * b.x; acc[3][1] += a.w * b.y; acc[3][2] += a.w * b.z; acc[3][3] += a.w * b.w;
    }
    #pragma unroll
    for (int ii = 0; ii < 4; ++ii) {
        float rs = 0.f;
        #pragma unroll
        for (int jj = 0; jj < 4; ++jj) {
            int j = j0 + tx * 4 + jj;
            if (j < cnt) rs += __expf(acc[ii][jj] * INV_TEMP);
        }
        atomicAdd(&red[ty * 4 + ii], rs);
    }
    __syncthreads();
    if (t < 64) atomicAdd(&ttlz[i0 + t], red[t]);
}

// ---------------- BPR + reg: block of 4 waves -> one float2 partial ----------------
__global__ void bpr_kernel(const int* __restrict__ users, const int* __restrict__ pos,
                           const int* __restrict__ neg,
                           const __half* __restrict__ A, const __half* __restrict__ B,
                           const __half* __restrict__ C,
                           const float* __restrict__ user_emb, const float* __restrict__ item_emb,
                           float2* __restrict__ partials) {
    __shared__ float2 wp[4];
    int gid = blockIdx.x * blockDim.x + threadIdx.x;
    int b = gid >> 6;
    int lane = gid & 63;
    int wid = (threadIdx.x >> 6);
    float lg = 0.f, rgsum = 0.f;
    if (b < NBATCH) {
        int u = users[b], p = pos[b], n = neg[b];
        size_t ru = (size_t)u * DD + lane;
        size_t rp = (size_t)(NU + p) * DD + lane;
        size_t rn = (size_t)(NU + n) * DD + lane;
        float ue = ((float)A[ru] + (float)B[ru] + (float)C[ru]) * (1.f / 3.f);
        float pe = ((float)A[rp] + (float)B[rp] + (float)C[rp]) * (1.f / 3.f);
        float ne = ((float)A[rn] + (float)B[rn] + (float)C[rn]) * (1.f / 3.f);
        float su = ue * ue, sp = pe * pe, sn = ne * ne, dp = ue * pe, dn = ue * ne;
        float u0 = user_emb[(size_t)u * DD + lane];
        float p0 = item_emb[(size_t)p * DD + lane];
        float n0 = item_emb[(size_t)n * DD + lane];
        float rg = u0 * u0 + p0 * p0 + n0 * n0;
        #pragma unroll
        for (int o = 32; o > 0; o >>= 1) {
            su += __shfl_xor(su, o); sp += __shfl_xor(sp, o); sn += __shfl_xor(sn, o);
            dp += __shfl_xor(dp, o); dn += __shfl_xor(dn, o); rg += __shfl_xor(rg, o);
        }
        float nu = fmaxf(sqrtf(su), 1e-12f);
        float np_ = fmaxf(sqrtf(sp), 1e-12f);
        float nn_ = fmaxf(sqrtf(sn), 1e-12f);
        float ps = dp / (nu * np_);
        float ns = dn / (nu * nn_);
        float xx = ps - ns;
        float sig = 1.f / (1.f + __expf(-xx));
        lg = logf(sig + 1e-6f);
        rgsum = rg;
    }
    if (lane == 0) wp[wid] = make_float2(lg, rgsum);
    __syncthreads();
    if (threadIdx.x == 0) {
        float2 s = wp[0];
        s.x += wp[1].x + wp[2].x + wp[3].x;
        s.y += wp[1].y + wp[2].y + wp[3].y;
        partials[blockIdx.x] = s;
    }
}

// ---------------- finalize: bpr partials + cl terms, all in one block ----------------
__global__ void finalize_kernel(const float2* __restrict__ partials,
                                const float* __restrict__ posv, const float* __restrict__ ttlv,
                                const int* __restrict__ cnts, float* __restrict__ out) {
    __shared__ float4 wsum[16];
    int t = threadIdx.x;   // 1024
    float mf = 0.f, rg = 0.f;
    if (t < BPR_BLOCKS) { float2 v = partials[t]; mf = v.x; rg = v.y; }
    int c0 = cnts[0], c1 = cnts[1];
    float clu = 0.f, cli = 0.f;
    for (int k = t; k < NBATCH; k += 1024) {
        if (k < c0) clu += -logf(posv[k] / ttlv[k] + 1e-5f);
        if (k < c1) cli += -logf(posv[NBATCH + k] / ttlv[NBATCH + k] + 1e-5f);
    }
    float4 v4 = make_float4(mf, rg, clu, cli);
    #pragma unroll
    for (int o = 32; o > 0; o >>= 1) {
        v4.x += __shfl_xor(v4.x, o); v4.y += __shfl_xor(v4.y, o);
        v4.z += __shfl_xor(v4.z, o); v4.w += __shfl_xor(v4.w, o);
    }
    if ((t & 63) == 0) wsum[t >> 6] = v4;
    __syncthreads();
    if (t == 0) {
        float a = 0.f, b = 0.f, c = 0.f, d = 0.f;
        #pragma unroll
        for (int k = 0; k < 16; ++k) { a += wsum[k].x; b += wsum[k].y; c += wsum[k].z; d += wsum[k].w; }
        out[0] = -a / (float)NBATCH;
        out[1] = 0.2f * (c / (float)c0 + d / (float)c1);
        out[2] = 1e-4f * 0.5f * b / (float)NBATCH;
    }
}

extern "C" void kernel_launch(void* const* d_in, const int* in_sizes, int n_in,
                              void* d_out, int out_size, void* d_ws, size_t ws_size,
                              hipStream_t stream) {
    const int*   users     = (const int*)d_in[0];
    const int*   pos_items = (const int*)d_in[1];
    const int*   neg_items = (const int*)d_in[2];
    const float* user_emb  = (const float*)d_in[3];
    const float* item_emb  = (const float*)d_in[4];
    const int*   rows      = (const int*)d_in[5];
    const int*   cols      = (const int*)d_in[6];
    const float* vals      = (const float*)d_in[7];
    const float* noise     = (const float*)d_in[8];
    float* out = (float*)d_out;
    const int E = in_sizes[5];

    // ---- workspace carve (256B aligned) ----
    char* w = (char*)d_ws;
    size_t off = 0;
    auto carve = [&](size_t bytes) { char* p = w + off; off = (off + bytes + 255) & ~(size_t)255; return p; };
    __half* bufX = (__half*)carve(ND * 2);
    __half* bufA = (__half*)carve(ND * 2);
    __half* bufB = (__half*)carve(ND * 2);
    __half* bufC = (__half*)carve(ND * 2);
    int2*  bedges  = (int2*)carve((size_t)E * 8);
    int2*  edges   = (int2*)carve((size_t)E * 8);
    int*   rstart  = (int*)carve((NT + 1) * 4);
    int*   cstart  = (int*)carve((NCB + 1) * 4);
    int*   ccur    = (int*)carve(NCB * 4);
    // ---- contiguous zero region ----
    char* zstart = w + off;
    int*   ccnt    = (int*)carve(NCB * 4);
    int*   cnts    = (int*)carve(2 * 4);
    float* ttl     = (float*)carve(2 * NBATCH * 4);
    int*   flags_u = (int*)carve(NU * 4);
    int*   flags_i = (int*)carve(NI * 4);
    size_t zbytes = (size_t)((w + off) - zstart);
    // ---- end zero region ----
    int* ulist   = (int*)carve(NBATCH * 4);
    int* ilist   = (int*)carve(NBATCH * 4);
    float* V1  = (float*)carve((size_t)2 * NBATCH * DD * 4);
    float* V2  = (float*)carve((size_t)2 * NBATCH * DD * 4);
    float* posv = (float*)carve(2 * NBATCH * 4);
    float2* bpr_part = (float2*)carve(BPR_BLOCKS * 8);

    hipMemsetAsync(zstart, 0, zbytes, stream);

    const int nTiles = (E + TILE - 1) / TILE;
    const int rowBlocks  = (NT * DD + 255) / 256;
    const int slotBlocks = (NBATCH * DD + 255) / 256;   // 1024
    const int cvtBlocks  = (int)((ND / 4 + 255) / 256);

    // ---- edge sort: coarse hist -> scan -> coarse bin -> fine sort (builds rstart) ----
    coarse_hist_kernel<<<nTiles, 256, 0, stream>>>(rows, E, ccnt);
    coarse_scan_kernel<<<1, 256, 0, stream>>>(ccnt, cstart, ccur, rstart, E);
    coarse_bin_kernel<<<nTiles, 256, 0, stream>>>(rows, cols, vals, E, ccur, bedges);
    fine_sort_kernel<<<NCB, 512, 0, stream>>>(cstart, bedges, edges, rstart);

    // ---- fp16 input concat ----
    concat_half_kernel<<<cvtBlocks, 256, 0, stream>>>(user_emb, item_emb, bufX);

    // ---- 3 propagation layers (perturb fused) ----
    spmm_csr_kernel<<<rowBlocks, 256, 0, stream>>>(rstart, edges, bufX, noise + 0 * ND, bufB);
    spmm_csr_kernel<<<rowBlocks, 256, 0, stream>>>(rstart, edges, bufB, noise + 1 * ND, bufC);
    spmm_csr_kernel<<<rowBlocks, 256, 0, stream>>>(rstart, edges, bufC, noise + 2 * ND, bufA);

    // ---- unique (dual) ----
    dim3 ugrid((NBATCH + 255) / 256, 2);
    unique_kernel<<<ugrid, 256, 0, stream>>>(users, pos_items, flags_u, flags_i, ulist, ilist, cnts);

    // ---- gather + normalize + pos scores (dual) ----
    dim3 ggrid(slotBlocks, 2);
    gather_cl_kernel<<<ggrid, 256, 0, stream>>>(ulist, ilist, cnts, bufA, bufB, bufC, V1, V2, posv);

    // ---- ttl sums (dual) ----
    dim3 tgrid(NBATCH / 64, NBATCH / 64, 2);
    ttl_kernel<<<tgrid, 256, 0, stream>>>(V1, V2, cnts, ttl);

    // ---- BPR + reg (two-stage) ----
    bpr_kernel<<<BPR_BLOCKS, 256, 0, stream>>>(users, pos_items, neg_items, bufA, bufB, bufC,
                                               user_emb, item_emb, bpr_part);

    // ---- finalize (absorbs cl reduction) ----
    finalize_kernel<<<1, 1024, 0, stream>>>(bpr_part, posv, ttl, cnts, out);
}

// Round 8
// 534.427 us; speedup vs baseline: 8.8514x; 1.2167x over previous
//
#include <hip/hip_runtime.h>
#include <hip/hip_fp16.h>
#include <math.h>

#define NU 50000
#define NI 50000
#define NT 100000
#define DD 64
#define NBATCH 4096
#define INV_TEMP 5.0f
#define EPS_ 0.2f

#define CBR 512                            // rows per coarse bucket
#define NCB ((NT + CBR - 1) / CBR)         // 196
#define TILE 8192                          // edges per phase-1 block
#define ND ((long long)NT * DD)            // 6,400,000
#define BPR_BLOCKS (NBATCH / 4)            // 1024 partials

typedef _Float16 half8 __attribute__((ext_vector_type(8)));
typedef float floatx4 __attribute__((ext_vector_type(4)));

// ---------------- coarse histogram: 196 buckets, LDS-aggregated ----------------
__global__ void coarse_hist_kernel(const int* __restrict__ rows, int E, int* __restrict__ ccnt) {
    __shared__ int h[NCB];
    int t = threadIdx.x;
    if (t < NCB) h[t] = 0;
    __syncthreads();
    int base = blockIdx.x * TILE;
    for (int it = 0; it < TILE / 256; ++it) {
        int e = base + it * 256 + t;
        if (e < E) atomicAdd(&h[rows[e] >> 9], 1);
    }
    __syncthreads();
    if (t < NCB && h[t]) atomicAdd(&ccnt[t], h[t]);
}

// ---------------- coarse scan: 196 entries -> cstart[197], ccur; set rstart[NT] ----------------
__global__ void coarse_scan_kernel(const int* __restrict__ ccnt, int* __restrict__ cstart,
                                   int* __restrict__ ccur, int* __restrict__ rstart, int E) {
    __shared__ int wsum[4];
    int t = threadIdx.x;   // 256
    int v = (t < NCB) ? ccnt[t] : 0;
    int lane = t & 63, wid = t >> 6;
    int x = v;
    #pragma unroll
    for (int o = 1; o < 64; o <<= 1) { int y = __shfl_up(x, o); if (lane >= o) x += y; }
    if (lane == 63) wsum[wid] = x;
    __syncthreads();
    if (t == 0) {
        int s = 0;
        #pragma unroll
        for (int k = 0; k < 4; ++k) { int tmp = wsum[k]; wsum[k] = s; s += tmp; }
    }
    __syncthreads();
    int ex = x - v + wsum[wid];
    if (t < NCB) { cstart[t] = ex; ccur[t] = ex; }
    if (t == 0) { cstart[NCB] = E; rstart[NT] = E; }
}

// ---------------- phase 1: bin edges into coarse buckets, block-owned runs ----------------
__global__ void coarse_bin_kernel(const int* __restrict__ rows, const int* __restrict__ cols,
                                  const float* __restrict__ vals, int E,
                                  int* __restrict__ ccur, int2* __restrict__ bedges) {
    __shared__ int h[NCB];
    __shared__ int cur[NCB];
    int t = threadIdx.x;
    if (t < NCB) h[t] = 0;
    __syncthreads();
    int base = blockIdx.x * TILE;
    for (int it = 0; it < TILE / 256; ++it) {
        int e = base + it * 256 + t;
        if (e < E) atomicAdd(&h[rows[e] >> 9], 1);
    }
    __syncthreads();
    if (t < NCB) {
        int c = h[t];
        cur[t] = c ? atomicAdd(&ccur[t], c) : 0;
    }
    __syncthreads();
    for (int it = 0; it < TILE / 256; ++it) {
        int e = base + it * 256 + t;
        if (e < E) {
            int r = rows[e];
            int cb = r >> 9;
            int p = atomicAdd(&cur[cb], 1);
            bedges[p] = make_int2(((r & 511) << 17) | cols[e], __float_as_int(vals[e]));
        }
    }
}

// ---------------- phase 2: per-coarse-bucket row sort + CSR offset build ----------------
__global__ void fine_sort_kernel(const int* __restrict__ cstart, const int2* __restrict__ bedges,
                                 int2* __restrict__ edges, int* __restrict__ rstart) {
    __shared__ int h[CBR];
    __shared__ int lcur[CBR];
    __shared__ int wsum[8];
    int b = blockIdx.x;
    int t = threadIdx.x;   // 512
    int r0 = b * CBR;
    int nrows = min(CBR, NT - r0);
    h[t] = 0;
    __syncthreads();
    int e0 = cstart[b];
    int e1 = cstart[b + 1];
    for (int k = e0 + t; k < e1; k += 512) atomicAdd(&h[bedges[k].x >> 17], 1);
    __syncthreads();
    int v = h[t];
    int lane = t & 63, wid = t >> 6;
    int x = v;
    #pragma unroll
    for (int o = 1; o < 64; o <<= 1) { int y = __shfl_up(x, o); if (lane >= o) x += y; }
    if (lane == 63) wsum[wid] = x;
    __syncthreads();
    if (t == 0) {
        int s = 0;
        #pragma unroll
        for (int k = 0; k < 8; ++k) { int tmp = wsum[k]; wsum[k] = s; s += tmp; }
    }
    __syncthreads();
    int gpos = e0 + x - v + wsum[wid];
    if (t < nrows) rstart[r0 + t] = gpos;
    lcur[t] = gpos;
    __syncthreads();
    for (int k = e0 + t; k < e1; k += 512) {
        int2 ed = bedges[k];
        int rl = ed.x >> 17;
        int p = atomicAdd(&lcur[rl], 1);
        edges[p] = make_int2(ed.x & 0x1FFFF, ed.y);
    }
}

// ---------------- fp32 concat -> fp16 (4 elems/thread) ----------------
__global__ void concat_half_kernel(const float* __restrict__ u, const float* __restrict__ it,
                                   __half* __restrict__ x0) {
    long long i = ((long long)blockIdx.x * 256 + threadIdx.x) * 4;
    if (i >= ND) return;
    long long half1 = (long long)NU * DD;
    float4 v = (i < half1) ? *(const float4*)(u + i) : *(const float4*)(it + (i - half1));
    __half2 h01 = __floats2half2_rn(v.x, v.y);
    __half2 h23 = __floats2half2_rn(v.z, v.w);
    uint2 q;
    q.x = *reinterpret_cast<uint*>(&h01);
    q.y = *reinterpret_cast<uint*>(&h23);
    *(uint2*)((ushort*)x0 + i) = q;
}

// ---------------- SpMM: wave per row, 32-edge chunks, 4 edges/group in flight ----------------
__global__ void spmm_csr_kernel(const int* __restrict__ rstart, const int2* __restrict__ edges,
                                const __half* __restrict__ x, const float* __restrict__ noise,
                                __half* __restrict__ y) {
    int gid = blockIdx.x * blockDim.x + threadIdx.x;
    int row = gid >> 6;
    int lane = gid & 63;
    if (row >= NT) return;
    int group = lane >> 3;     // 0..7
    int sub = lane & 7;        // dims sub*8 .. sub*8+7
    int s0 = rstart[row];
    int s1 = rstart[row + 1];
    const ushort* xs = (const ushort*)x;
    float acc[8] = {0.f, 0.f, 0.f, 0.f, 0.f, 0.f, 0.f, 0.f};
    for (int base = s0; base < s1; base += 32) {
        int k = base + (lane & 31);
        int2 ed = (k < s1) ? edges[k] : make_int2(0, 0);   // sentinel: col 0, val 0
        #pragma unroll
        for (int j = 0; j < 4; ++j) {
            int ei = j * 8 + group;   // 0..31
            int c = __shfl(ed.x, ei);
            float v = __int_as_float(__shfl(ed.y, ei));
            uint4 q = *(const uint4*)(xs + ((size_t)c << 6) + (sub << 3));
            __half2 h0 = *reinterpret_cast<__half2*>(&q.x);
            __half2 h1 = *reinterpret_cast<__half2*>(&q.y);
            __half2 h2 = *reinterpret_cast<__half2*>(&q.z);
            __half2 h3 = *reinterpret_cast<__half2*>(&q.w);
            float2 f0 = __half22float2(h0);
            float2 f1 = __half22float2(h1);
            float2 f2 = __half22float2(h2);
            float2 f3 = __half22float2(h3);
            acc[0] += v * f0.x; acc[1] += v * f0.y;
            acc[2] += v * f1.x; acc[3] += v * f1.y;
            acc[4] += v * f2.x; acc[5] += v * f2.y;
            acc[6] += v * f3.x; acc[7] += v * f3.y;
        }
    }
    // reduce across the 8 groups (lane bits 3..5)
    #pragma unroll
    for (int o = 8; o < 64; o <<= 1) {
        #pragma unroll
        for (int d = 0; d < 8; ++d) acc[d] += __shfl_xor(acc[d], o);
    }
    // perturb
    const float4* nf = (const float4*)(noise + (size_t)row * DD);
    float4 na = nf[sub * 2];
    float4 nb = nf[sub * 2 + 1];
    float s = na.x * na.x + na.y * na.y + na.z * na.z + na.w * na.w
            + nb.x * nb.x + nb.y * nb.y + nb.z * nb.z + nb.w * nb.w;
    #pragma unroll
    for (int o = 1; o < 8; o <<= 1) s += __shfl_xor(s, o);
    float inv = EPS_ / fmaxf(sqrtf(s), 1e-12f);
    float nd_[8] = {na.x, na.y, na.z, na.w, nb.x, nb.y, nb.z, nb.w};
    float r[8];
    #pragma unroll
    for (int d = 0; d < 8; ++d) {
        float a = acc[d];
        float sg = (a > 0.f) ? 1.f : ((a < 0.f) ? -1.f : 0.f);
        r[d] = a + sg * nd_[d] * inv;
    }
    if (group == 0) {
        __half2 o0 = __floats2half2_rn(r[0], r[1]);
        __half2 o1 = __floats2half2_rn(r[2], r[3]);
        __half2 o2 = __floats2half2_rn(r[4], r[5]);
        __half2 o3 = __floats2half2_rn(r[6], r[7]);
        uint4 q;
        q.x = *reinterpret_cast<uint*>(&o0);
        q.y = *reinterpret_cast<uint*>(&o1);
        q.z = *reinterpret_cast<uint*>(&o2);
        q.w = *reinterpret_cast<uint*>(&o3);
        *(uint4*)((ushort*)y + ((size_t)row << 6) + (sub << 3)) = q;
    }
}

// ---------------- unique via flags, wave-aggregated; dual (y=0 users, y=1 items) ----------------
__global__ void unique_kernel(const int* __restrict__ users, const int* __restrict__ pos_items,
                              int* __restrict__ flags_u, int* __restrict__ flags_i,
                              int* __restrict__ ulist, int* __restrict__ ilist,
                              int* __restrict__ cnts) {
    int which = blockIdx.y;
    const int* in = which ? pos_items : users;
    int* flags = which ? flags_i : flags_u;
    int* list = which ? ilist : ulist;
    int* count = cnts + which;
    int t = blockIdx.x * blockDim.x + threadIdx.x;
    bool isnew = false;
    int u = 0;
    if (t < NBATCH) {
        u = in[t];
        isnew = (atomicExch(&flags[u], 1) == 0);
    }
    unsigned long long mask = __ballot(isnew);
    int nnew = __popcll(mask);
    int lane = threadIdx.x & 63;
    int base = 0;
    if (nnew) {
        int leader = __ffsll((long long)mask) - 1;
        if (lane == leader) base = atomicAdd(count, nnew);
        base = __shfl(base, leader);
        if (isnew) {
            int rank = __popcll(mask & ((1ull << lane) - 1ull));
            list[base + rank] = u;
        }
    }
}

// ---------------- gather + normalize -> fp16 V1/V2 (MFMA operands); dual via blockIdx.y ----------------
__global__ void gather_cl_kernel(const int* __restrict__ ulist, const int* __restrict__ ilist,
                                 const int* __restrict__ cnts,
                                 const __half* __restrict__ A, const __half* __restrict__ B,
                                 const __half* __restrict__ C,
                                 _Float16* __restrict__ V1, _Float16* __restrict__ V2,
                                 float* __restrict__ posv) {
    int which = blockIdx.y;
    const int* list = which ? ilist : ulist;
    int baseRow = which ? NU : 0;
    int cnt = cnts[which];
    _Float16* V1z = V1 + (size_t)which * NBATCH * DD;
    _Float16* V2z = V2 + (size_t)which * NBATCH * DD;
    float* posz = posv + which * NBATCH;
    int gid = blockIdx.x * blockDim.x + threadIdx.x;
    int s = gid >> 6;
    int lane = gid & 63;
    if (s >= NBATCH) return;
    float v1 = 0.f, v2 = 0.f;
    if (s < cnt) {
        size_t r = (size_t)(baseRow + list[s]) * DD + lane;
        v1 = ((float)A[r] + (float)B[r] + (float)C[r]) * (1.f / 3.f);
        v2 = (float)B[r];
    }
    float s1 = v1 * v1, s2 = v2 * v2;
    #pragma unroll
    for (int o = 32; o > 0; o >>= 1) { s1 += __shfl_xor(s1, o); s2 += __shfl_xor(s2, o); }
    v1 = v1 / fmaxf(sqrtf(s1), 1e-12f);
    v2 = v2 / fmaxf(sqrtf(s2), 1e-12f);
    V1z[s * DD + lane] = (_Float16)v1;
    V2z[s * DD + lane] = (_Float16)v2;
    float d = v1 * v2;
    #pragma unroll
    for (int o = 32; o > 0; o >>= 1) d += __shfl_xor(d, o);
    if (lane == 0) posz[s] = __expf(d * INV_TEMP);
}

// ---------------- ttl via MFMA: wave = 16-row i-tile x 256-col j-chunk, no LDS ----------------
// a/b frag layout (16x16x32): X[n=lane&15][k=(lane>>4)*8 + j]; C/D: col=lane&15, row=(lane>>4)*4+reg.
__global__ void ttl_mfma_kernel(const _Float16* __restrict__ V1, const _Float16* __restrict__ V2,
                                const int* __restrict__ cnts, float* __restrict__ ttl) {
    int z = blockIdx.z;
    const _Float16* Az = V1 + (size_t)z * NBATCH * DD;
    const _Float16* Bz = V2 + (size_t)z * NBATCH * DD;
    float* ttlz = ttl + z * NBATCH;
    int cnt = cnts[z];
    int wave = threadIdx.x >> 6;
    int lane = threadIdx.x & 63;
    int n = lane & 15;
    int quad = lane >> 4;
    int itile = blockIdx.x * 4 + wave;
    int i0 = itile << 4;
    const _Float16* arow = Az + (size_t)(i0 + n) * DD + quad * 8;
    half8 a0 = *(const half8*)(arow);
    half8 a1 = *(const half8*)(arow + 32);
    float rs0 = 0.f, rs1 = 0.f, rs2 = 0.f, rs3 = 0.f;
    int jt0 = blockIdx.y * 16;
    int jtEnd = min(jt0 + 16, (cnt + 15) >> 4);
    bool colv_base;
    for (int jt = jt0; jt < jtEnd; ++jt) {
        int j0 = jt << 4;
        const _Float16* brow = Bz + (size_t)(j0 + n) * DD + quad * 8;
        half8 b0 = *(const half8*)(brow);
        half8 b1 = *(const half8*)(brow + 32);
        floatx4 acc = {0.f, 0.f, 0.f, 0.f};
        acc = __builtin_amdgcn_mfma_f32_16x16x32_f16(a0, b0, acc, 0, 0, 0);
        acc = __builtin_amdgcn_mfma_f32_16x16x32_f16(a1, b1, acc, 0, 0, 0);
        bool valid = (j0 + n) < cnt;
        rs0 += valid ? __expf(acc[0] * INV_TEMP) : 0.f;
        rs1 += valid ? __expf(acc[1] * INV_TEMP) : 0.f;
        rs2 += valid ? __expf(acc[2] * INV_TEMP) : 0.f;
        rs3 += valid ? __expf(acc[3] * INV_TEMP) : 0.f;
    }
    // reduce over the 16 columns held by this quad (lane bits 0..3)
    #pragma unroll
    for (int o = 1; o < 16; o <<= 1) {
        rs0 += __shfl_xor(rs0, o);
        rs1 += __shfl_xor(rs1, o);
        rs2 += __shfl_xor(rs2, o);
        rs3 += __shfl_xor(rs3, o);
    }
    if (n == 0) {
        int r0 = i0 + quad * 4;
        atomicAdd(&ttlz[r0 + 0], rs0);
        atomicAdd(&ttlz[r0 + 1], rs1);
        atomicAdd(&ttlz[r0 + 2], rs2);
        atomicAdd(&ttlz[r0 + 3], rs3);
    }
}

// ---------------- BPR + reg: block of 4 waves -> one float2 partial ----------------
__global__ void bpr_kernel(const int* __restrict__ users, const int* __restrict__ pos,
                           const int* __restrict__ neg,
                           const __half* __restrict__ A, const __half* __restrict__ B,
                           const __half* __restrict__ C,
                           const float* __restrict__ user_emb, const float* __restrict__ item_emb,
                           float2* __restrict__ partials) {
    __shared__ float2 wp[4];
    int gid = blockIdx.x * blockDim.x + threadIdx.x;
    int b = gid >> 6;
    int lane = gid & 63;
    int wid = (threadIdx.x >> 6);
    float lg = 0.f, rgsum = 0.f;
    if (b < NBATCH) {
        int u = users[b], p = pos[b], n = neg[b];
        size_t ru = (size_t)u * DD + lane;
        size_t rp = (size_t)(NU + p) * DD + lane;
        size_t rn = (size_t)(NU + n) * DD + lane;
        float ue = ((float)A[ru] + (float)B[ru] + (float)C[ru]) * (1.f / 3.f);
        float pe = ((float)A[rp] + (float)B[rp] + (float)C[rp]) * (1.f / 3.f);
        float ne = ((float)A[rn] + (float)B[rn] + (float)C[rn]) * (1.f / 3.f);
        float su = ue * ue, sp = pe * pe, sn = ne * ne, dp = ue * pe, dn = ue * ne;
        float u0 = user_emb[(size_t)u * DD + lane];
        float p0 = item_emb[(size_t)p * DD + lane];
        float n0 = item_emb[(size_t)n * DD + lane];
        float rg = u0 * u0 + p0 * p0 + n0 * n0;
        #pragma unroll
        for (int o = 32; o > 0; o >>= 1) {
            su += __shfl_xor(su, o); sp += __shfl_xor(sp, o); sn += __shfl_xor(sn, o);
            dp += __shfl_xor(dp, o); dn += __shfl_xor(dn, o); rg += __shfl_xor(rg, o);
        }
        float nu = fmaxf(sqrtf(su), 1e-12f);
        float np_ = fmaxf(sqrtf(sp), 1e-12f);
        float nn_ = fmaxf(sqrtf(sn), 1e-12f);
        float ps = dp / (nu * np_);
        float ns = dn / (nu * nn_);
        float xx = ps - ns;
        float sig = 1.f / (1.f + __expf(-xx));
        lg = logf(sig + 1e-6f);
        rgsum = rg;
    }
    if (lane == 0) wp[wid] = make_float2(lg, rgsum);
    __syncthreads();
    if (threadIdx.x == 0) {
        float2 s = wp[0];
        s.x += wp[1].x + wp[2].x + wp[3].x;
        s.y += wp[1].y + wp[2].y + wp[3].y;
        partials[blockIdx.x] = s;
    }
}

// ---------------- finalize: bpr partials + cl terms, all in one block ----------------
__global__ void finalize_kernel(const float2* __restrict__ partials,
                                const float* __restrict__ posv, const float* __restrict__ ttlv,
                                const int* __restrict__ cnts, float* __restrict__ out) {
    __shared__ float4 wsum[16];
    int t = threadIdx.x;   // 1024
    float mf = 0.f, rg = 0.f;
    if (t < BPR_BLOCKS) { float2 v = partials[t]; mf = v.x; rg = v.y; }
    int c0 = cnts[0], c1 = cnts[1];
    float clu = 0.f, cli = 0.f;
    for (int k = t; k < NBATCH; k += 1024) {
        if (k < c0) clu += -logf(posv[k] / ttlv[k] + 1e-5f);
        if (k < c1) cli += -logf(posv[NBATCH + k] / ttlv[NBATCH + k] + 1e-5f);
    }
    float4 v4 = make_float4(mf, rg, clu, cli);
    #pragma unroll
    for (int o = 32; o > 0; o >>= 1) {
        v4.x += __shfl_xor(v4.x, o); v4.y += __shfl_xor(v4.y, o);
        v4.z += __shfl_xor(v4.z, o); v4.w += __shfl_xor(v4.w, o);
    }
    if ((t & 63) == 0) wsum[t >> 6] = v4;
    __syncthreads();
    if (t == 0) {
        float a = 0.f, b = 0.f, c = 0.f, d = 0.f;
        #pragma unroll
        for (int k = 0; k < 16; ++k) { a += wsum[k].x; b += wsum[k].y; c += wsum[k].z; d += wsum[k].w; }
        out[0] = -a / (float)NBATCH;
        out[1] = 0.2f * (c / (float)c0 + d / (float)c1);
        out[2] = 1e-4f * 0.5f * b / (float)NBATCH;
    }
}

extern "C" void kernel_launch(void* const* d_in, const int* in_sizes, int n_in,
                              void* d_out, int out_size, void* d_ws, size_t ws_size,
                              hipStream_t stream) {
    const int*   users     = (const int*)d_in[0];
    const int*   pos_items = (const int*)d_in[1];
    const int*   neg_items = (const int*)d_in[2];
    const float* user_emb  = (const float*)d_in[3];
    const float* item_emb  = (const float*)d_in[4];
    const int*   rows      = (const int*)d_in[5];
    const int*   cols      = (const int*)d_in[6];
    const float* vals      = (const float*)d_in[7];
    const float* noise     = (const float*)d_in[8];
    float* out = (float*)d_out;
    const int E = in_sizes[5];

    // ---- workspace carve (256B aligned) ----
    char* w = (char*)d_ws;
    size_t off = 0;
    auto carve = [&](size_t bytes) { char* p = w + off; off = (off + bytes + 255) & ~(size_t)255; return p; };
    __half* bufX = (__half*)carve(ND * 2);
    __half* bufA = (__half*)carve(ND * 2);
    __half* bufB = (__half*)carve(ND * 2);
    __half* bufC = (__half*)carve(ND * 2);
    int2*  bedges  = (int2*)carve((size_t)E * 8);
    int2*  edges   = (int2*)carve((size_t)E * 8);
    int*   rstart  = (int*)carve((NT + 1) * 4);
    int*   cstart  = (int*)carve((NCB + 1) * 4);
    int*   ccur    = (int*)carve(NCB * 4);
    // ---- contiguous zero region ----
    char* zstart = w + off;
    int*   ccnt    = (int*)carve(NCB * 4);
    int*   cnts    = (int*)carve(2 * 4);
    float* ttl     = (float*)carve(2 * NBATCH * 4);
    int*   flags_u = (int*)carve(NU * 4);
    int*   flags_i = (int*)carve(NI * 4);
    size_t zbytes = (size_t)((w + off) - zstart);
    // ---- end zero region ----
    int* ulist   = (int*)carve(NBATCH * 4);
    int* ilist   = (int*)carve(NBATCH * 4);
    _Float16* V1 = (_Float16*)carve((size_t)2 * NBATCH * DD * 2);
    _Float16* V2 = (_Float16*)carve((size_t)2 * NBATCH * DD * 2);
    float* posv = (float*)carve(2 * NBATCH * 4);
    float2* bpr_part = (float2*)carve(BPR_BLOCKS * 8);

    hipMemsetAsync(zstart, 0, zbytes, stream);

    const int nTiles = (E + TILE - 1) / TILE;
    const int rowBlocks  = (NT * DD + 255) / 256;
    const int slotBlocks = (NBATCH * DD + 255) / 256;   // 1024
    const int cvtBlocks  = (int)((ND / 4 + 255) / 256);

    // ---- edge sort: coarse hist -> scan -> coarse bin -> fine sort (builds rstart) ----
    coarse_hist_kernel<<<nTiles, 256, 0, stream>>>(rows, E, ccnt);
    coarse_scan_kernel<<<1, 256, 0, stream>>>(ccnt, cstart, ccur, rstart, E);
    coarse_bin_kernel<<<nTiles, 256, 0, stream>>>(rows, cols, vals, E, ccur, bedges);
    fine_sort_kernel<<<NCB, 512, 0, stream>>>(cstart, bedges, edges, rstart);

    // ---- fp16 input concat ----
    concat_half_kernel<<<cvtBlocks, 256, 0, stream>>>(user_emb, item_emb, bufX);

    // ---- 3 propagation layers (perturb fused) ----
    spmm_csr_kernel<<<rowBlocks, 256, 0, stream>>>(rstart, edges, bufX, noise + 0 * ND, bufB);
    spmm_csr_kernel<<<rowBlocks, 256, 0, stream>>>(rstart, edges, bufB, noise + 1 * ND, bufC);
    spmm_csr_kernel<<<rowBlocks, 256, 0, stream>>>(rstart, edges, bufC, noise + 2 * ND, bufA);

    // ---- unique (dual) ----
    dim3 ugrid((NBATCH + 255) / 256, 2);
    unique_kernel<<<ugrid, 256, 0, stream>>>(users, pos_items, flags_u, flags_i, ulist, ilist, cnts);

    // ---- gather + normalize + pos scores (dual) ----
    dim3 ggrid(slotBlocks, 2);
    gather_cl_kernel<<<ggrid, 256, 0, stream>>>(ulist, ilist, cnts, bufA, bufB, bufC, V1, V2, posv);

    // ---- ttl via MFMA: grid (i-tiles/4, j-chunks, 2) ----
    dim3 tgrid(NBATCH / 16 / 4, 16, 2);
    ttl_mfma_kernel<<<tgrid, 256, 0, stream>>>(V1, V2, cnts, ttl);

    // ---- BPR + reg (two-stage) ----
    bpr_kernel<<<BPR_BLOCKS, 256, 0, stream>>>(users, pos_items, neg_items, bufA, bufB, bufC,
                                               user_emb, item_emb, bpr_part);

    // ---- finalize (absorbs cl reduction) ----
    finalize_kernel<<<1, 1024, 0, stream>>>(bpr_part, posv, ttl, cnts, out);
}

// Round 9
// 492.285 us; speedup vs baseline: 9.6092x; 1.0856x over previous
//
#include <hip/hip_runtime.h>
#include <hip/hip_fp16.h>
#include <math.h>

#define NU 50000
#define NI 50000
#define NT 100000
#define DD 64
#define NBATCH 4096
#define INV_TEMP 5.0f
#define EPS_ 0.2f

#define CBR 512                            // rows per coarse bucket
#define NCB ((NT + CBR - 1) / CBR)         // 196
#define CAP 18000                          // fixed edge capacity per coarse bucket (mean 16327, 13 sigma)
#define TILE 8192                          // edges per phase-1 block
#define ND ((long long)NT * DD)            // 6,400,000
#define BPR_BLOCKS (NBATCH / 4)            // 1024 partials

typedef _Float16 half8 __attribute__((ext_vector_type(8)));
typedef float floatx4 __attribute__((ext_vector_type(4)));

// ---------------- phase 1: bin edges into fixed-capacity coarse buckets ----------------
// packed: x = (rl9 << 17) | col, y = val fp32 bits
__global__ void coarse_bin_kernel(const int* __restrict__ rows, const int* __restrict__ cols,
                                  const float* __restrict__ vals, int E,
                                  int* __restrict__ ccur, int2* __restrict__ bedges) {
    __shared__ int h[NCB];
    __shared__ int cur[NCB];
    int t = threadIdx.x;
    if (t < NCB) h[t] = 0;
    __syncthreads();
    int base = blockIdx.x * TILE;
    for (int it = 0; it < TILE / 256; ++it) {
        int e = base + it * 256 + t;
        if (e < E) atomicAdd(&h[rows[e] >> 9], 1);
    }
    __syncthreads();
    if (t < NCB) {
        int c = h[t];
        cur[t] = t * CAP + (c ? atomicAdd(&ccur[t], c) : 0);   // one global atomic per (block,bucket)
    }
    __syncthreads();
    for (int it = 0; it < TILE / 256; ++it) {
        int e = base + it * 256 + t;
        if (e < E) {
            int r = rows[e];
            int cb = r >> 9;
            int p = atomicAdd(&cur[cb], 1);
            bedges[p] = make_int2(((r & 511) << 17) | cols[e], __float_as_int(vals[e]));
        }
    }
}

// ---------------- phase 2: per-bucket row sort; builds rstart + deg; packs val as half2 ----------------
__global__ void fine_sort_kernel(const int* __restrict__ ccur, const int2* __restrict__ bedges,
                                 int2* __restrict__ edges, int* __restrict__ rstart,
                                 int* __restrict__ deg) {
    __shared__ int h[CBR];
    __shared__ int lcur[CBR];
    __shared__ int wsum[8];
    int b = blockIdx.x;
    int t = threadIdx.x;   // 512
    int r0 = b * CBR;
    int nrows = min(CBR, NT - r0);
    h[t] = 0;
    __syncthreads();
    int e0 = b * CAP;
    int e1 = e0 + ccur[b];
    for (int k = e0 + t; k < e1; k += 512) atomicAdd(&h[bedges[k].x >> 17], 1);
    __syncthreads();
    int v = h[t];
    int lane = t & 63, wid = t >> 6;
    int x = v;
    #pragma unroll
    for (int o = 1; o < 64; o <<= 1) { int y = __shfl_up(x, o); if (lane >= o) x += y; }
    if (lane == 63) wsum[wid] = x;
    __syncthreads();
    if (t == 0) {
        int s = 0;
        #pragma unroll
        for (int k = 0; k < 8; ++k) { int tmp = wsum[k]; wsum[k] = s; s += tmp; }
    }
    __syncthreads();
    int gpos = e0 + x - v + wsum[wid];
    if (t < nrows) { rstart[r0 + t] = gpos; deg[r0 + t] = v; }
    lcur[t] = gpos;
    __syncthreads();
    for (int k = e0 + t; k < e1; k += 512) {
        int2 ed = bedges[k];
        int rl = ed.x >> 17;
        int p = atomicAdd(&lcur[rl], 1);
        float vf = __int_as_float(ed.y);
        __half hv = __float2half(vf);
        __half2 hh = __half2(hv, hv);
        edges[p] = make_int2(ed.x & 0x1FFFF, *reinterpret_cast<int*>(&hh));
    }
}

// ---------------- fp32 concat -> fp16 (4 elems/thread) ----------------
__global__ void concat_half_kernel(const float* __restrict__ u, const float* __restrict__ it,
                                   __half* __restrict__ x0) {
    long long i = ((long long)blockIdx.x * 256 + threadIdx.x) * 4;
    if (i >= ND) return;
    long long half1 = (long long)NU * DD;
    float4 v = (i < half1) ? *(const float4*)(u + i) : *(const float4*)(it + (i - half1));
    __half2 h01 = __floats2half2_rn(v.x, v.y);
    __half2 h23 = __floats2half2_rn(v.z, v.w);
    uint2 q;
    q.x = *reinterpret_cast<uint*>(&h01);
    q.y = *reinterpret_cast<uint*>(&h23);
    *(uint2*)((ushort*)x0 + i) = q;
}

// ---------------- SpMM: wave per row, 32-edge chunks, packed-fp16 accumulate ----------------
__global__ void spmm_csr_kernel(const int* __restrict__ rstart, const int* __restrict__ deg,
                                const int2* __restrict__ edges,
                                const __half* __restrict__ x, const float* __restrict__ noise,
                                __half* __restrict__ y) {
    int gid = blockIdx.x * blockDim.x + threadIdx.x;
    int row = gid >> 6;
    int lane = gid & 63;
    if (row >= NT) return;
    int group = lane >> 3;     // 0..7: edge slot within each 8
    int sub = lane & 7;        // dims sub*8 .. sub*8+7
    int s0 = rstart[row];
    int dg = deg[row];
    const ushort* xs = (const ushort*)x;
    __half2 acc0 = __half2(__half(0.f), __half(0.f));
    __half2 acc1 = acc0, acc2 = acc0, acc3 = acc0;
    for (int base = 0; base < dg; base += 32) {
        int k = base + (lane & 31);
        int2 ed = (k < dg) ? edges[s0 + k] : make_int2(0, 0);   // sentinel: col 0, val half2(0,0)
        #pragma unroll
        for (int j = 0; j < 4; ++j) {
            int ei = j * 8 + group;   // 0..31
            int c = __shfl(ed.x, ei);
            int vb = __shfl(ed.y, ei);
            __half2 vv = *reinterpret_cast<__half2*>(&vb);
            uint4 q = *(const uint4*)(xs + ((size_t)c << 6) + (sub << 3));
            acc0 = __hfma2(*reinterpret_cast<__half2*>(&q.x), vv, acc0);
            acc1 = __hfma2(*reinterpret_cast<__half2*>(&q.y), vv, acc1);
            acc2 = __hfma2(*reinterpret_cast<__half2*>(&q.z), vv, acc2);
            acc3 = __hfma2(*reinterpret_cast<__half2*>(&q.w), vv, acc3);
        }
    }
    float acc[8];
    {
        float2 f0 = __half22float2(acc0);
        float2 f1 = __half22float2(acc1);
        float2 f2 = __half22float2(acc2);
        float2 f3 = __half22float2(acc3);
        acc[0] = f0.x; acc[1] = f0.y; acc[2] = f1.x; acc[3] = f1.y;
        acc[4] = f2.x; acc[5] = f2.y; acc[6] = f3.x; acc[7] = f3.y;
    }
    // reduce across the 8 groups (lane bits 3..5)
    #pragma unroll
    for (int o = 8; o < 64; o <<= 1) {
        #pragma unroll
        for (int d = 0; d < 8; ++d) acc[d] += __shfl_xor(acc[d], o);
    }
    // perturb
    const float4* nf = (const float4*)(noise + (size_t)row * DD);
    float4 na = nf[sub * 2];
    float4 nb = nf[sub * 2 + 1];
    float s = na.x * na.x + na.y * na.y + na.z * na.z + na.w * na.w
            + nb.x * nb.x + nb.y * nb.y + nb.z * nb.z + nb.w * nb.w;
    #pragma unroll
    for (int o = 1; o < 8; o <<= 1) s += __shfl_xor(s, o);
    float inv = EPS_ / fmaxf(sqrtf(s), 1e-12f);
    float nd_[8] = {na.x, na.y, na.z, na.w, nb.x, nb.y, nb.z, nb.w};
    float r[8];
    #pragma unroll
    for (int d = 0; d < 8; ++d) {
        float a = acc[d];
        float sg = (a > 0.f) ? 1.f : ((a < 0.f) ? -1.f : 0.f);
        r[d] = a + sg * nd_[d] * inv;
    }
    if (group == 0) {
        __half2 o0 = __floats2half2_rn(r[0], r[1]);
        __half2 o1 = __floats2half2_rn(r[2], r[3]);
        __half2 o2 = __floats2half2_rn(r[4], r[5]);
        __half2 o3 = __floats2half2_rn(r[6], r[7]);
        uint4 q;
        q.x = *reinterpret_cast<uint*>(&o0);
        q.y = *reinterpret_cast<uint*>(&o1);
        q.z = *reinterpret_cast<uint*>(&o2);
        q.w = *reinterpret_cast<uint*>(&o3);
        *(uint4*)((ushort*)y + ((size_t)row << 6) + (sub << 3)) = q;
    }
}

// ---------------- unique via flags, wave-aggregated; dual (y=0 users, y=1 items) ----------------
__global__ void unique_kernel(const int* __restrict__ users, const int* __restrict__ pos_items,
                              int* __restrict__ flags_u, int* __restrict__ flags_i,
                              int* __restrict__ ulist, int* __restrict__ ilist,
                              int* __restrict__ cnts) {
    int which = blockIdx.y;
    const int* in = which ? pos_items : users;
    int* flags = which ? flags_i : flags_u;
    int* list = which ? ilist : ulist;
    int* count = cnts + which;
    int t = blockIdx.x * blockDim.x + threadIdx.x;
    bool isnew = false;
    int u = 0;
    if (t < NBATCH) {
        u = in[t];
        isnew = (atomicExch(&flags[u], 1) == 0);
    }
    unsigned long long mask = __ballot(isnew);
    int nnew = __popcll(mask);
    int lane = threadIdx.x & 63;
    int base = 0;
    if (nnew) {
        int leader = __ffsll((long long)mask) - 1;
        if (lane == leader) base = atomicAdd(count, nnew);
        base = __shfl(base, leader);
        if (isnew) {
            int rank = __popcll(mask & ((1ull << lane) - 1ull));
            list[base + rank] = u;
        }
    }
}

// ---------------- gather + normalize -> fp16 V1/V2 (MFMA operands); dual via blockIdx.y ----------------
__global__ void gather_cl_kernel(const int* __restrict__ ulist, const int* __restrict__ ilist,
                                 const int* __restrict__ cnts,
                                 const __half* __restrict__ A, const __half* __restrict__ B,
                                 const __half* __restrict__ C,
                                 _Float16* __restrict__ V1, _Float16* __restrict__ V2,
                                 float* __restrict__ posv) {
    int which = blockIdx.y;
    const int* list = which ? ilist : ulist;
    int baseRow = which ? NU : 0;
    int cnt = cnts[which];
    _Float16* V1z = V1 + (size_t)which * NBATCH * DD;
    _Float16* V2z = V2 + (size_t)which * NBATCH * DD;
    float* posz = posv + which * NBATCH;
    int gid = blockIdx.x * blockDim.x + threadIdx.x;
    int s = gid >> 6;
    int lane = gid & 63;
    if (s >= NBATCH) return;
    float v1 = 0.f, v2 = 0.f;
    if (s < cnt) {
        size_t r = (size_t)(baseRow + list[s]) * DD + lane;
        v1 = ((float)A[r] + (float)B[r] + (float)C[r]) * (1.f / 3.f);
        v2 = (float)B[r];
    }
    float s1 = v1 * v1, s2 = v2 * v2;
    #pragma unroll
    for (int o = 32; o > 0; o >>= 1) { s1 += __shfl_xor(s1, o); s2 += __shfl_xor(s2, o); }
    v1 = v1 / fmaxf(sqrtf(s1), 1e-12f);
    v2 = v2 / fmaxf(sqrtf(s2), 1e-12f);
    V1z[s * DD + lane] = (_Float16)v1;
    V2z[s * DD + lane] = (_Float16)v2;
    float d = v1 * v2;
    #pragma unroll
    for (int o = 32; o > 0; o >>= 1) d += __shfl_xor(d, o);
    if (lane == 0) posz[s] = __expf(d * INV_TEMP);
}

// ---------------- ttl via MFMA: wave = 16-row i-tile x 256-col j-chunk, no LDS ----------------
__global__ void ttl_mfma_kernel(const _Float16* __restrict__ V1, const _Float16* __restrict__ V2,
                                const int* __restrict__ cnts, float* __restrict__ ttl) {
    int z = blockIdx.z;
    const _Float16* Az = V1 + (size_t)z * NBATCH * DD;
    const _Float16* Bz = V2 + (size_t)z * NBATCH * DD;
    float* ttlz = ttl + z * NBATCH;
    int cnt = cnts[z];
    int wave = threadIdx.x >> 6;
    int lane = threadIdx.x & 63;
    int n = lane & 15;
    int quad = lane >> 4;
    int itile = blockIdx.x * 4 + wave;
    int i0 = itile << 4;
    const _Float16* arow = Az + (size_t)(i0 + n) * DD + quad * 8;
    half8 a0 = *(const half8*)(arow);
    half8 a1 = *(const half8*)(arow + 32);
    float rs0 = 0.f, rs1 = 0.f, rs2 = 0.f, rs3 = 0.f;
    int jt0 = blockIdx.y * 16;
    int jtEnd = min(jt0 + 16, (cnt + 15) >> 4);
    for (int jt = jt0; jt < jtEnd; ++jt) {
        int j0 = jt << 4;
        const _Float16* brow = Bz + (size_t)(j0 + n) * DD + quad * 8;
        half8 b0 = *(const half8*)(brow);
        half8 b1 = *(const half8*)(brow + 32);
        floatx4 acc = {0.f, 0.f, 0.f, 0.f};
        acc = __builtin_amdgcn_mfma_f32_16x16x32_f16(a0, b0, acc, 0, 0, 0);
        acc = __builtin_amdgcn_mfma_f32_16x16x32_f16(a1, b1, acc, 0, 0, 0);
        bool valid = (j0 + n) < cnt;
        rs0 += valid ? __expf(acc[0] * INV_TEMP) : 0.f;
        rs1 += valid ? __expf(acc[1] * INV_TEMP) : 0.f;
        rs2 += valid ? __expf(acc[2] * INV_TEMP) : 0.f;
        rs3 += valid ? __expf(acc[3] * INV_TEMP) : 0.f;
    }
    #pragma unroll
    for (int o = 1; o < 16; o <<= 1) {
        rs0 += __shfl_xor(rs0, o);
        rs1 += __shfl_xor(rs1, o);
        rs2 += __shfl_xor(rs2, o);
        rs3 += __shfl_xor(rs3, o);
    }
    if (n == 0) {
        int r0 = i0 + quad * 4;
        atomicAdd(&ttlz[r0 + 0], rs0);
        atomicAdd(&ttlz[r0 + 1], rs1);
        atomicAdd(&ttlz[r0 + 2], rs2);
        atomicAdd(&ttlz[r0 + 3], rs3);
    }
}

// ---------------- BPR + reg: block of 4 waves -> one float2 partial ----------------
__global__ void bpr_kernel(const int* __restrict__ users, const int* __restrict__ pos,
                           const int* __restrict__ neg,
                           const __half* __restrict__ A, const __half* __restrict__ B,
                           const __half* __restrict__ C,
                           const float* __restrict__ user_emb, const float* __restrict__ item_emb,
                           float2* __restrict__ partials) {
    __shared__ float2 wp[4];
    int gid = blockIdx.x * blockDim.x + threadIdx.x;
    int b = gid >> 6;
    int lane = gid & 63;
    int wid = (threadIdx.x >> 6);
    float lg = 0.f, rgsum = 0.f;
    if (b < NBATCH) {
        int u = users[b], p = pos[b], n = neg[b];
        size_t ru = (size_t)u * DD + lane;
        size_t rp = (size_t)(NU + p) * DD + lane;
        size_t rn = (size_t)(NU + n) * DD + lane;
        float ue = ((float)A[ru] + (float)B[ru] + (float)C[ru]) * (1.f / 3.f);
        float pe = ((float)A[rp] + (float)B[rp] + (float)C[rp]) * (1.f / 3.f);
        float ne = ((float)A[rn] + (float)B[rn] + (float)C[rn]) * (1.f / 3.f);
        float su = ue * ue, sp = pe * pe, sn = ne * ne, dp = ue * pe, dn = ue * ne;
        float u0 = user_emb[(size_t)u * DD + lane];
        float p0 = item_emb[(size_t)p * DD + lane];
        float n0 = item_emb[(size_t)n * DD + lane];
        float rg = u0 * u0 + p0 * p0 + n0 * n0;
        #pragma unroll
        for (int o = 32; o > 0; o >>= 1) {
            su += __shfl_xor(su, o); sp += __shfl_xor(sp, o); sn += __shfl_xor(sn, o);
            dp += __shfl_xor(dp, o); dn += __shfl_xor(dn, o); rg += __shfl_xor(rg, o);
        }
        float nu = fmaxf(sqrtf(su), 1e-12f);
        float np_ = fmaxf(sqrtf(sp), 1e-12f);
        float nn_ = fmaxf(sqrtf(sn), 1e-12f);
        float ps = dp / (nu * np_);
        float ns = dn / (nu * nn_);
        float xx = ps - ns;
        float sig = 1.f / (1.f + __expf(-xx));
        lg = logf(sig + 1e-6f);
        rgsum = rg;
    }
    if (lane == 0) wp[wid] = make_float2(lg, rgsum);
    __syncthreads();
    if (threadIdx.x == 0) {
        float2 s = wp[0];
        s.x += wp[1].x + wp[2].x + wp[3].x;
        s.y += wp[1].y + wp[2].y + wp[3].y;
        partials[blockIdx.x] = s;
    }
}

// ---------------- finalize: bpr partials + cl terms, all in one block ----------------
__global__ void finalize_kernel(const float2* __restrict__ partials,
                                const float* __restrict__ posv, const float* __restrict__ ttlv,
                                const int* __restrict__ cnts, float* __restrict__ out) {
    __shared__ float4 wsum[16];
    int t = threadIdx.x;   // 1024
    float mf = 0.f, rg = 0.f;
    if (t < BPR_BLOCKS) { float2 v = partials[t]; mf = v.x; rg = v.y; }
    int c0 = cnts[0], c1 = cnts[1];
    float clu = 0.f, cli = 0.f;
    for (int k = t; k < NBATCH; k += 1024) {
        if (k < c0) clu += -logf(posv[k] / ttlv[k] + 1e-5f);
        if (k < c1) cli += -logf(posv[NBATCH + k] / ttlv[NBATCH + k] + 1e-5f);
    }
    float4 v4 = make_float4(mf, rg, clu, cli);
    #pragma unroll
    for (int o = 32; o > 0; o >>= 1) {
        v4.x += __shfl_xor(v4.x, o); v4.y += __shfl_xor(v4.y, o);
        v4.z += __shfl_xor(v4.z, o); v4.w += __shfl_xor(v4.w, o);
    }
    if ((t & 63) == 0) wsum[t >> 6] = v4;
    __syncthreads();
    if (t == 0) {
        float a = 0.f, b = 0.f, c = 0.f, d = 0.f;
        #pragma unroll
        for (int k = 0; k < 16; ++k) { a += wsum[k].x; b += wsum[k].y; c += wsum[k].z; d += wsum[k].w; }
        out[0] = -a / (float)NBATCH;
        out[1] = 0.2f * (c / (float)c0 + d / (float)c1);
        out[2] = 1e-4f * 0.5f * b / (float)NBATCH;
    }
}

extern "C" void kernel_launch(void* const* d_in, const int* in_sizes, int n_in,
                              void* d_out, int out_size, void* d_ws, size_t ws_size,
                              hipStream_t stream) {
    const int*   users     = (const int*)d_in[0];
    const int*   pos_items = (const int*)d_in[1];
    const int*   neg_items = (const int*)d_in[2];
    const float* user_emb  = (const float*)d_in[3];
    const float* item_emb  = (const float*)d_in[4];
    const int*   rows      = (const int*)d_in[5];
    const int*   cols      = (const int*)d_in[6];
    const float* vals      = (const float*)d_in[7];
    const float* noise     = (const float*)d_in[8];
    float* out = (float*)d_out;
    const int E = in_sizes[5];

    // ---- workspace carve (256B aligned) ----
    char* w = (char*)d_ws;
    size_t off = 0;
    auto carve = [&](size_t bytes) { char* p = w + off; off = (off + bytes + 255) & ~(size_t)255; return p; };
    __half* bufX = (__half*)carve(ND * 2);
    __half* bufA = (__half*)carve(ND * 2);
    __half* bufB = (__half*)carve(ND * 2);
    __half* bufC = (__half*)carve(ND * 2);
    int2*  bedges  = (int2*)carve((size_t)NCB * CAP * 8);
    int2*  edges   = (int2*)carve((size_t)NCB * CAP * 8);
    int*   rstart  = (int*)carve(NT * 4);
    int*   deg     = (int*)carve(NT * 4);
    // ---- contiguous zero region ----
    char* zstart = w + off;
    int*   ccur    = (int*)carve(NCB * 4);
    int*   cnts    = (int*)carve(2 * 4);
    float* ttl     = (float*)carve(2 * NBATCH * 4);
    int*   flags_u = (int*)carve(NU * 4);
    int*   flags_i = (int*)carve(NI * 4);
    size_t zbytes = (size_t)((w + off) - zstart);
    // ---- end zero region ----
    int* ulist   = (int*)carve(NBATCH * 4);
    int* ilist   = (int*)carve(NBATCH * 4);
    _Float16* V1 = (_Float16*)carve((size_t)2 * NBATCH * DD * 2);
    _Float16* V2 = (_Float16*)carve((size_t)2 * NBATCH * DD * 2);
    float* posv = (float*)carve(2 * NBATCH * 4);
    float2* bpr_part = (float2*)carve(BPR_BLOCKS * 8);

    hipMemsetAsync(zstart, 0, zbytes, stream);

    const int nTiles = (E + TILE - 1) / TILE;
    const int rowBlocks  = (NT * DD + 255) / 256;
    const int slotBlocks = (NBATCH * DD + 255) / 256;   // 1024
    const int cvtBlocks  = (int)((ND / 4 + 255) / 256);

    // ---- edge sort: coarse bin (fixed-capacity runs) -> fine sort (builds rstart + deg) ----
    coarse_bin_kernel<<<nTiles, 256, 0, stream>>>(rows, cols, vals, E, ccur, bedges);
    fine_sort_kernel<<<NCB, 512, 0, stream>>>(ccur, bedges, edges, rstart, deg);

    // ---- fp16 input concat ----
    concat_half_kernel<<<cvtBlocks, 256, 0, stream>>>(user_emb, item_emb, bufX);

    // ---- 3 propagation layers (perturb fused) ----
    spmm_csr_kernel<<<rowBlocks, 256, 0, stream>>>(rstart, deg, edges, bufX, noise + 0 * ND, bufB);
    spmm_csr_kernel<<<rowBlocks, 256, 0, stream>>>(rstart, deg, edges, bufB, noise + 1 * ND, bufC);
    spmm_csr_kernel<<<rowBlocks, 256, 0, stream>>>(rstart, deg, edges, bufC, noise + 2 * ND, bufA);

    // ---- unique (dual) ----
    dim3 ugrid((NBATCH + 255) / 256, 2);
    unique_kernel<<<ugrid, 256, 0, stream>>>(users, pos_items, flags_u, flags_i, ulist, ilist, cnts);

    // ---- gather + normalize + pos scores (dual) ----
    dim3 ggrid(slotBlocks, 2);
    gather_cl_kernel<<<ggrid, 256, 0, stream>>>(ulist, ilist, cnts, bufA, bufB, bufC, V1, V2, posv);

    // ---- ttl via MFMA: grid (i-tiles/4, j-chunks, 2) ----
    dim3 tgrid(NBATCH / 16 / 4, 16, 2);
    ttl_mfma_kernel<<<tgrid, 256, 0, stream>>>(V1, V2, cnts, ttl);

    // ---- BPR + reg (two-stage) ----
    bpr_kernel<<<BPR_BLOCKS, 256, 0, stream>>>(users, pos_items, neg_items, bufA, bufB, bufC,
                                               user_emb, item_emb, bpr_part);

    // ---- finalize (absorbs cl reduction) ----
    finalize_kernel<<<1, 1024, 0, stream>>>(bpr_part, posv, ttl, cnts, out);
}